// Round 3
// baseline (1279.140 us; speedup 1.0000x reference)
//
#include <hip/hip_runtime.h>
#include <hip/hip_cooperative_groups.h>
#include <cstdint>
#include <cstddef>

namespace cg = cooperative_groups;

typedef __attribute__((ext_vector_type(8))) short short8;
typedef __attribute__((ext_vector_type(4))) float f32x4;
typedef __attribute__((ext_vector_type(2))) float f32x2;

#define NBLK 512        // edge-chunk blocks for fallback hist/scatter (pow2)
#define NBLK_SHIFT 9

__device__ inline unsigned short f2bf(float f) {
  union { float f; unsigned int u; } x; x.f = f;
  unsigned int r = x.u + 0x7FFFu + ((x.u >> 16) & 1u);  // round-to-nearest-even
  return (unsigned short)(r >> 16);
}
__device__ inline float bf2f(unsigned short s) {
  union { unsigned int u; float f; } x; x.u = ((unsigned int)s) << 16;
  return x.f;
}

// ============================================================================
// MEGA cooperative kernel: entire pipeline in one launch, 12 grid.sync phases.
// CSR build simplified: global-atomic degree count -> 2-level scan -> atomic
// cursor scatter (drops the packed[] round trip of the fallback path).
// ============================================================================

struct MegaParams {
  const float* x;
  const int* rows; const int* cols; const int* labels;
  const float* W1; const float* b1; const float* W2; const float* b2;
  const float* W3; const float* b3;
  const float* lW1; const float* lb1; const float* lW2; const float* lb2;
  unsigned char* A8; unsigned short* H;
  unsigned short* Wt1; unsigned short* Wt2; unsigned short* Wt3;
  float* dinv; int* offsets; int* deg; int* cur;
  int* sorted; int* partials; float* labelsum; float* pmsum;
  float* p; float* loss;
  int N, E, Npad, NCH;
};

template <int K, bool F32IN>
__device__ void gemm_phase(const MegaParams& P, const void* hv,
                           const unsigned short* Wt, unsigned char* out,
                           unsigned short (*tile)[16 * 68]) {
  int w = threadIdx.x >> 6, lane = threadIdx.x & 63;
  int m = lane & 15, quad = lane >> 4;
  int ntiles = P.Npad >> 6;
  unsigned short* tw = tile[w];
  for (int tb = blockIdx.x; tb < ntiles; tb += gridDim.x) {
    int m0 = tb * 64 + w * 16;
    int rowA = m0 + m;
    bool rowOK = rowA < P.N;
    f32x4 acc[4] = {{0.f,0.f,0.f,0.f},{0.f,0.f,0.f,0.f},{0.f,0.f,0.f,0.f},{0.f,0.f,0.f,0.f}};
#pragma unroll
    for (int kc = 0; kc < K / 32; ++kc) {
      short8 a = {0, 0, 0, 0, 0, 0, 0, 0};
      if (rowOK) {
        if (F32IN) {
          const float* hp = (const float*)hv + (size_t)rowA * K + kc * 32 + quad * 8;
          float4 p0 = ((const float4*)hp)[0];
          float4 p1 = ((const float4*)hp)[1];
          a[0] = (short)f2bf(p0.x); a[1] = (short)f2bf(p0.y);
          a[2] = (short)f2bf(p0.z); a[3] = (short)f2bf(p0.w);
          a[4] = (short)f2bf(p1.x); a[5] = (short)f2bf(p1.y);
          a[6] = (short)f2bf(p1.z); a[7] = (short)f2bf(p1.w);
        } else {
          a = *(const short8*)((const unsigned short*)hv + (size_t)rowA * K + kc * 32 + quad * 8);
        }
      }
#pragma unroll
      for (int t = 0; t < 4; ++t) {
        short8 b = *(const short8*)(Wt + (size_t)(t * 16 + m) * K + kc * 32 + quad * 8);
        acc[t] = __builtin_amdgcn_mfma_f32_16x16x32_bf16(a, b, acc[t], 0, 0, 0);
      }
    }
#pragma unroll
    for (int r = 0; r < 4; ++r) {
      int row = quad * 4 + r;
      int gr = m0 + row;
      float dv = P.dinv[gr < P.N ? gr : 0];
#pragma unroll
      for (int t = 0; t < 4; ++t)
        tw[row * 68 + t * 16 + m] = f2bf(acc[t][r] * dv);
    }
#pragma unroll
    for (int pq = 0; pq < 4; ++pq) {
      int row = pq * 4 + (lane >> 4);
      int ch = lane & 15;  // 4-feature chunk
      int gr = m0 + row;
      if (gr < P.N) {
        uint2 v = *(const uint2*)(tw + row * 68 + ch * 4);
        float f0 = bf2f((unsigned short)(v.x & 0xFFFFu));
        float f1 = bf2f((unsigned short)(v.x >> 16));
        float f2 = bf2f((unsigned short)(v.y & 0xFFFFu));
        float f3 = bf2f((unsigned short)(v.y >> 16));
        int pk = 0;
        pk = __builtin_amdgcn_cvt_pk_fp8_f32(f0, f1, pk, false);
        pk = __builtin_amdgcn_cvt_pk_fp8_f32(f2, f3, pk, true);
        *(unsigned int*)(out + (size_t)gr * 64 + ch * 4) = (unsigned int)pk;
      }
    }
  }
}

__device__ void agg_phase(const MegaParams& P, const unsigned char* A8,
                          const float* bias, unsigned short* out) {
  int ngr = (P.N + 31) >> 5;
  int l = threadIdx.x & 7;           // 8B chunk (8 feats) of the 64B row
  int obase = threadIdx.x & 56;      // octet base lane within the wave
  for (int g = blockIdx.x; g < ngr; g += gridDim.x) {
    int c = g * 32 + (threadIdx.x >> 3);  // one node per 8-lane octet
    if (c >= P.N) continue;
    int s = P.offsets[c], e = P.offsets[c + 1];
    float dc = P.dinv[c];
    uint2 svr = *(const uint2*)(A8 + ((size_t)c << 6) + l * 8);
    f32x2 a0 = {0.f, 0.f}, a1 = {0.f, 0.f}, a2 = {0.f, 0.f}, a3 = {0.f, 0.f};
    for (int base = s; base < e; base += 16) {
      int i0 = base + l, i1 = base + 8 + l;
      int r0 = (i0 < e) ? __builtin_nontemporal_load(P.sorted + i0) : 0;
      int r1 = (i1 < e) ? __builtin_nontemporal_load(P.sorted + i1) : 0;
      int cnt = e - base; if (cnt > 16) cnt = 16;
      int rj[16];
#pragma unroll
      for (int t = 0; t < 8; ++t)  rj[t] = __shfl(r0, obase + t);
#pragma unroll
      for (int t = 8; t < 16; ++t) rj[t] = __shfl(r1, obase + (t - 8));
#pragma unroll
      for (int t = 0; t < 16; ++t) {
        if (t < cnt) {
          uint2 v = *(const uint2*)(A8 + ((size_t)(unsigned int)rj[t] << 6) + l * 8);
          a0 += __builtin_amdgcn_cvt_pk_f32_fp8((int)v.x, false);
          a1 += __builtin_amdgcn_cvt_pk_f32_fp8((int)v.x, true);
          a2 += __builtin_amdgcn_cvt_pk_f32_fp8((int)v.y, false);
          a3 += __builtin_amdgcn_cvt_pk_f32_fp8((int)v.y, true);
        }
      }
    }
    f32x2 s0 = __builtin_amdgcn_cvt_pk_f32_fp8((int)svr.x, false);
    f32x2 s1 = __builtin_amdgcn_cvt_pk_f32_fp8((int)svr.x, true);
    f32x2 s2 = __builtin_amdgcn_cvt_pk_f32_fp8((int)svr.y, false);
    f32x2 s3 = __builtin_amdgcn_cvt_pk_f32_fp8((int)svr.y, true);
    float acc[8] = {a0[0] + s0[0], a0[1] + s0[1], a1[0] + s1[0], a1[1] + s1[1],
                    a2[0] + s2[0], a2[1] + s2[1], a3[0] + s3[0], a3[1] + s3[1]};
    const float* bp = bias + l * 8;
    short8 ov;
#pragma unroll
    for (int q = 0; q < 8; ++q) {
      float v = fmaf(acc[q], dc, bp[q]);
      ov[q] = (short)f2bf(v > 0.f ? v : 0.f);
    }
    *(short8*)(out + (size_t)c * 64 + l * 8) = ov;
  }
}

__global__ __launch_bounds__(256, 4) void mega(MegaParams P) {
  cg::grid_group grid = cg::this_grid();
  __shared__ unsigned short tile[4][16 * 68];   // 8704 B, aliased by scan phases
  int* itmp = (int*)&tile[0][0];
  float* ftmp = (float*)&tile[0][0];
  const int bid = blockIdx.x, tid = threadIdx.x;
  const int G = gridDim.x, stride = G * 256;

  // ---- P0: zero deg, transpose Wt1..3, per-block label sums, zero loss ----
  for (int i = bid * 256 + tid; i < P.N; i += stride) P.deg[i] = 0;
  for (int i = bid * 256 + tid; i < 16384; i += stride) {
    if (i < 8192)       { int n = i >> 7, k = i & 127; P.Wt1[i] = f2bf(P.W1[k * 64 + n]); }
    else if (i < 12288) { int j = i - 8192,  n = j >> 6, k = j & 63; P.Wt2[j] = f2bf(P.W2[k * 64 + n]); }
    else                { int j = i - 12288, n = j >> 6, k = j & 63; P.Wt3[j] = f2bf(P.W3[k * 64 + n]); }
  }
  {
    int chunk = (P.N + G - 1) / G;
    int ls = bid * chunk;
    int le = ls + chunk; if (le > P.N) le = P.N;
    float v = 0.f;
    for (int i = ls + tid; i < le; i += 256) v += (float)P.labels[i];
#pragma unroll
    for (int o = 32; o > 0; o >>= 1) v += __shfl_down(v, o);
    if ((tid & 63) == 0) ftmp[tid >> 6] = v;
    __syncthreads();
    if (tid == 0) P.labelsum[bid] = ftmp[0] + ftmp[1] + ftmp[2] + ftmp[3];
  }
  if (bid == 0 && tid == 0) *P.loss = 0.f;
  grid.sync();

  // ---- P1: degree count (global atomics) ----
  for (int e = bid * 256 + tid; e < P.E; e += stride)
    atomicAdd(&P.deg[P.cols[e]], 1);
  grid.sync();

  // ---- P2: per-chunk degree sums; one block reduces labelsum -> pmsum ----
  if (bid < P.NCH) {
    int node = bid * 256 + tid;
    int v = (node < P.N) ? P.deg[node] : 0;
#pragma unroll
    for (int o = 32; o > 0; o >>= 1) v += __shfl_down(v, o);
    if ((tid & 63) == 0) itmp[tid >> 6] = v;
    __syncthreads();
    if (tid == 0) P.partials[bid] = itmp[0] + itmp[1] + itmp[2] + itmp[3];
  } else if (bid == P.NCH) {
    float v = 0.f;
    for (int i = tid; i < G; i += 256) v += P.labelsum[i];
#pragma unroll
    for (int o = 32; o > 0; o >>= 1) v += __shfl_down(v, o);
    if ((tid & 63) == 0) ftmp[tid >> 6] = v;
    __syncthreads();
    if (tid == 0) *P.pmsum = ftmp[0] + ftmp[1] + ftmp[2] + ftmp[3];
  }
  grid.sync();

  // ---- P3: block 0 exclusive-scans partials[NCH] ----
  if (bid == 0) {
    int carry = 0;
    for (int base = 0; base < P.NCH; base += 256) {
      int i = base + tid;
      int v = (i < P.NCH) ? P.partials[i] : 0;
      itmp[tid] = v;
      __syncthreads();
      int incl = v;
      for (int o = 1; o < 256; o <<= 1) {
        int t = (tid >= o) ? itmp[tid - o] : 0;
        __syncthreads();
        incl += t;
        itmp[tid] = incl;
        __syncthreads();
      }
      int total = itmp[255];
      if (i < P.NCH) P.partials[i] = carry + incl - v;
      carry += total;
      __syncthreads();
    }
  }
  grid.sync();

  // ---- P4: offsets / cursors / dinv ----
  if (bid < P.NCH) {
    int node = bid * 256 + tid;
    int d = (node < P.N) ? P.deg[node] : 0;
    itmp[tid] = d;
    __syncthreads();
    int incl = d;
    for (int o = 1; o < 256; o <<= 1) {
      int t = (tid >= o) ? itmp[tid - o] : 0;
      __syncthreads();
      incl += t;
      itmp[tid] = incl;
      __syncthreads();
    }
    int off = P.partials[bid] + incl - d;
    if (node < P.N) {
      P.offsets[node] = off;
      P.cur[node] = off;
      P.dinv[node] = rsqrtf((float)(d + 1));  // +1 self loop
    }
  }
  if (bid == 0 && tid == 0) P.offsets[P.N] = P.E;
  grid.sync();

  // ---- P5: scatter via per-node atomic cursors ----
  for (int e = bid * 256 + tid; e < P.E; e += stride) {
    int c = P.cols[e];
    int pos = atomicAdd(&P.cur[c], 1);
    P.sorted[pos] = P.rows[e];
  }
  grid.sync();

  // ---- layers ----
  gemm_phase<128, true>(P, P.x, P.Wt1, P.A8, tile);
  grid.sync();
  agg_phase(P, P.A8, P.b1, P.H);
  grid.sync();
  gemm_phase<64, false>(P, P.H, P.Wt2, P.A8, tile);
  grid.sync();
  agg_phase(P, P.A8, P.b2, P.H);
  grid.sync();
  gemm_phase<64, false>(P, P.H, P.Wt3, P.A8, tile);
  grid.sync();
  agg_phase(P, P.A8, P.b3, P.H);
  grid.sync();

  // ---- P12: MLP head + sigmoid + weighted BCE ----
  {
    float contrib = 0.f;
    float pm = *P.pmsum / (float)P.N;
    for (int n = bid * 256 + tid; n < P.N; n += stride) {
      float acc[8];
#pragma unroll
      for (int j = 0; j < 8; ++j) acc[j] = P.lb1[j];
      const unsigned short* hr = P.H + (size_t)n * 64;
#pragma unroll
      for (int ch = 0; ch < 8; ++ch) {
        short8 hv8 = ((const short8*)hr)[ch];
#pragma unroll
        for (int q = 0; q < 8; ++q) {
          float v = bf2f((unsigned short)hv8[q]);
          int k = ch * 8 + q;
#pragma unroll
          for (int j = 0; j < 8; ++j) acc[j] = fmaf(v, P.lW1[k * 8 + j], acc[j]);
        }
      }
      float s = P.lb2[0];
#pragma unroll
      for (int j = 0; j < 8; ++j) {
        float a = acc[j] > 0.f ? acc[j] : 0.f;
        s = fmaf(a, P.lW2[j], s);
      }
      float pv = 1.0f / (1.0f + expf(-s));
      P.p[n] = pv;
      float y = (float)P.labels[n];
      float w = y * (1.f - pm) + (1.f - y) * pm;
      float pc = fminf(fmaxf(pv, 1e-7f), 1.f - 1e-7f);
      float bce = -(y * logf(pc) + (1.f - y) * logf(1.f - pc));
      contrib += w * bce / (float)P.N;
    }
#pragma unroll
    for (int o = 32; o > 0; o >>= 1) contrib += __shfl_down(contrib, o);
    __syncthreads();
    if ((tid & 63) == 0) ftmp[tid >> 6] = contrib;
    __syncthreads();
    if (tid == 0) atomicAdd(P.loss, ftmp[0] + ftmp[1] + ftmp[2] + ftmp[3]);
  }
}

// ============================================================================
// FALLBACK path: verbatim round-2 kernels (used only if cooperative launch
// is unavailable). Proven at 300 µs.
// ============================================================================

__global__ __launch_bounds__(256) void hist_kernel(const int* __restrict__ cols,
                                                   int* __restrict__ histG,
                                                   const int* __restrict__ labels,
                                                   float* __restrict__ labelsum,
                                                   const float* __restrict__ W1,
                                                   const float* __restrict__ W2,
                                                   const float* __restrict__ W3,
                                                   unsigned short* __restrict__ Wt1,
                                                   unsigned short* __restrict__ Wt2,
                                                   unsigned short* __restrict__ Wt3,
                                                   int E, int N, int NBUCK) {
  __shared__ int h[512];
  if (blockIdx.x < 3) {
    const float* W; unsigned short* Wt; int K;
    if (blockIdx.x == 0)      { W = W1; Wt = Wt1; K = 128; }
    else if (blockIdx.x == 1) { W = W2; Wt = Wt2; K = 64; }
    else                      { W = W3; Wt = Wt3; K = 64; }
    int total = K * 64;
    for (int i = threadIdx.x; i < total; i += 256) {
      int n = i / K, k = i - n * K;
      Wt[i] = f2bf(W[k * 64 + n]);
    }
  }
  {
    int chunkL = (N + NBLK - 1) / NBLK;
    int ls = blockIdx.x * chunkL;
    int le = min(N, ls + chunkL);
    float v = 0.f;
    for (int i = ls + threadIdx.x; i < le; i += 256) v += (float)labels[i];
#pragma unroll
    for (int o = 32; o > 0; o >>= 1) v += __shfl_down(v, o);
    __shared__ float sl[4];
    if ((threadIdx.x & 63) == 0) sl[threadIdx.x >> 6] = v;
    __syncthreads();
    if (threadIdx.x == 0) labelsum[blockIdx.x] = sl[0] + sl[1] + sl[2] + sl[3];
  }
  for (int i = threadIdx.x; i < NBUCK; i += 256) h[i] = 0;
  __syncthreads();
  int chunk = (E + NBLK - 1) / NBLK;
  int s = blockIdx.x * chunk;
  int e = min(E, s + chunk);
  for (int i = s + threadIdx.x; i < e; i += 256) atomicAdd(&h[cols[i] >> 8], 1);
  __syncthreads();
  for (int i = threadIdx.x; i < NBUCK; i += 256)
    histG[blockIdx.x * NBUCK + i] = h[i];
}

__global__ __launch_bounds__(256) void scan_partials_t(const int* __restrict__ histG,
                                                       int* __restrict__ partials,
                                                       int total, int NBUCK) {
  int i = blockIdx.x * 256 + threadIdx.x;
  int v = 0;
  if (i < total) {
    int bucket = i >> NBLK_SHIFT, blk = i & (NBLK - 1);
    v = histG[blk * NBUCK + bucket];
  }
#pragma unroll
  for (int o = 32; o > 0; o >>= 1) v += __shfl_down(v, o);
  __shared__ int s[4];
  if ((threadIdx.x & 63) == 0) s[threadIdx.x >> 6] = v;
  __syncthreads();
  if (threadIdx.x == 0) partials[blockIdx.x] = s[0] + s[1] + s[2] + s[3];
}

__global__ __launch_bounds__(256) void scan_block(int* __restrict__ partials, int nb,
                                                  float* __restrict__ loss,
                                                  const float* __restrict__ labelsum,
                                                  float* __restrict__ pmsum) {
  __shared__ int tmp[256];
  __shared__ int carry;
  int tid = threadIdx.x;
  {
    float v = 0.f;
    for (int i = tid; i < NBLK; i += 256) v += labelsum[i];
#pragma unroll
    for (int o = 32; o > 0; o >>= 1) v += __shfl_down(v, o);
    __shared__ float sl[4];
    if ((tid & 63) == 0) sl[tid >> 6] = v;
    __syncthreads();
    if (tid == 0) *pmsum = sl[0] + sl[1] + sl[2] + sl[3];
  }
  if (tid == 0) { carry = 0; *loss = 0.f; }
  __syncthreads();
  for (int base = 0; base < nb; base += 256) {
    int i = base + tid;
    int v = (i < nb) ? partials[i] : 0;
    tmp[tid] = v;
    __syncthreads();
    int incl = v;
    for (int o = 1; o < 256; o <<= 1) {
      int t = (tid >= o) ? tmp[tid - o] : 0;
      __syncthreads();
      incl += t;
      tmp[tid] = incl;
      __syncthreads();
    }
    int total = tmp[255];
    int c = carry;
    if (i < nb) partials[i] = c + incl - v;
    __syncthreads();
    if (tid == 0) carry = c + total;
    __syncthreads();
  }
}

__global__ __launch_bounds__(256) void scan_final_t(const int* __restrict__ histG,
                                                    const int* __restrict__ partials,
                                                    int* __restrict__ scannedG,
                                                    int total, int NBUCK) {
  __shared__ int tmp[256];
  int tid = threadIdx.x;
  int i = blockIdx.x * 256 + tid;
  int bucket = i >> NBLK_SHIFT, blk = i & (NBLK - 1);
  int v = (i < total) ? histG[blk * NBUCK + bucket] : 0;
  tmp[tid] = v;
  __syncthreads();
  int incl = v;
  for (int o = 1; o < 256; o <<= 1) {
    int t = (tid >= o) ? tmp[tid - o] : 0;
    __syncthreads();
    incl += t;
    tmp[tid] = incl;
    __syncthreads();
  }
  if (i < total) scannedG[blk * NBUCK + bucket] = partials[blockIdx.x] + incl - v;
}

__global__ __launch_bounds__(256) void scatter_kernel(const int* __restrict__ rows,
                                                      const int* __restrict__ cols,
                                                      const int* __restrict__ scannedG,
                                                      unsigned int* __restrict__ packed,
                                                      int E, int NBUCK) {
  __shared__ int cur[512];
  for (int i = threadIdx.x; i < NBUCK; i += 256)
    cur[i] = scannedG[blockIdx.x * NBUCK + i];
  __syncthreads();
  int chunk = (E + NBLK - 1) / NBLK;
  int s = blockIdx.x * chunk;
  int e = min(E, s + chunk);
  for (int i = s + threadIdx.x; i < e; i += 256) {
    int c = cols[i];
    int r = rows[i];
    int pos = atomicAdd(&cur[c >> 8], 1);
    packed[pos] = ((unsigned int)(c & 255) << 24) | (unsigned int)r;
  }
}

__global__ __launch_bounds__(1024) void csr_finalize(const unsigned int* __restrict__ packed,
                                                     const int* __restrict__ scannedG,
                                                     int* __restrict__ sorted_src,
                                                     int* __restrict__ offsets,
                                                     float* __restrict__ dinv,
                                                     int N, int E, int NBUCK) {
  __shared__ int h[256];
  __shared__ int tmp[256];
  __shared__ int cur[256];
  int b = blockIdx.x;
  int tid = threadIdx.x;
  int base = scannedG[b];
  int end = (b + 1 < NBUCK) ? scannedG[b + 1] : E;
  if (tid < 256) h[tid] = 0;
  __syncthreads();
  for (int i = base + tid; i < end; i += 1024)
    atomicAdd(&h[packed[i] >> 24], 1);
  __syncthreads();
  if (tid < 256) {
    int v = h[tid];
    tmp[tid] = v;
  }
  __syncthreads();
  if (tid < 256) {
    int v = h[tid];
    int incl = v;
    for (int o = 1; o < 256; o <<= 1) {
      int t = (tid >= o) ? tmp[tid - o] : 0;
      __syncthreads();
      incl += t;
      tmp[tid] = incl;
      __syncthreads();
    }
    int excl = incl - v;
    int node = b * 256 + tid;
    if (node < N) {
      offsets[node] = base + excl;
      dinv[node] = rsqrtf((float)(v + 1));
    }
    cur[tid] = base + excl;
    if (b == NBUCK - 1 && tid == 0) offsets[N] = E;
  } else {
    for (int o = 1; o < 256; o <<= 1) { __syncthreads(); __syncthreads(); }
  }
  __syncthreads();
  for (int i = base + tid; i < end; i += 1024) {
    unsigned int p = packed[i];
    int pos = atomicAdd(&cur[p >> 24], 1);
    sorted_src[pos] = (int)(p & 0xFFFFFFu);
  }
}

template <int K, bool F32IN>
__global__ __launch_bounds__(256) void mfma_gemm(const void* __restrict__ hv,
                                                 const unsigned short* __restrict__ Wt,
                                                 const float* __restrict__ dinv,
                                                 unsigned char* __restrict__ out, int N) {
  __shared__ unsigned short tile[4][16 * 68];
  int w = threadIdx.x >> 6, lane = threadIdx.x & 63;
  int m = lane & 15, quad = lane >> 4;
  int m0 = blockIdx.x * 64 + w * 16;
  int rowA = m0 + m;
  bool rowOK = rowA < N;
  f32x4 acc[4] = {{0.f,0.f,0.f,0.f},{0.f,0.f,0.f,0.f},{0.f,0.f,0.f,0.f},{0.f,0.f,0.f,0.f}};
#pragma unroll
  for (int kc = 0; kc < K / 32; ++kc) {
    short8 a = {0, 0, 0, 0, 0, 0, 0, 0};
    if (rowOK) {
      if (F32IN) {
        const float* hp = (const float*)hv + (size_t)rowA * K + kc * 32 + quad * 8;
        float4 p0 = ((const float4*)hp)[0];
        float4 p1 = ((const float4*)hp)[1];
        a[0] = (short)f2bf(p0.x); a[1] = (short)f2bf(p0.y);
        a[2] = (short)f2bf(p0.z); a[3] = (short)f2bf(p0.w);
        a[4] = (short)f2bf(p1.x); a[5] = (short)f2bf(p1.y);
        a[6] = (short)f2bf(p1.z); a[7] = (short)f2bf(p1.w);
      } else {
        a = *(const short8*)((const unsigned short*)hv + (size_t)rowA * K + kc * 32 + quad * 8);
      }
    }
#pragma unroll
    for (int t = 0; t < 4; ++t) {
      short8 b = *(const short8*)(Wt + (size_t)(t * 16 + m) * K + kc * 32 + quad * 8);
      acc[t] = __builtin_amdgcn_mfma_f32_16x16x32_bf16(a, b, acc[t], 0, 0, 0);
    }
  }
  unsigned short* tw = tile[w];
#pragma unroll
  for (int r = 0; r < 4; ++r) {
    int row = quad * 4 + r;
    int gr = m0 + row;
    float dv = dinv[gr < N ? gr : 0];
#pragma unroll
    for (int t = 0; t < 4; ++t)
      tw[row * 68 + t * 16 + m] = f2bf(acc[t][r] * dv);
  }
#pragma unroll
  for (int p = 0; p < 4; ++p) {
    int row = p * 4 + (lane >> 4);
    int ch = lane & 15;
    int gr = m0 + row;
    if (gr < N) {
      uint2 v = *(const uint2*)(tw + row * 68 + ch * 4);
      float f0 = bf2f((unsigned short)(v.x & 0xFFFFu));
      float f1 = bf2f((unsigned short)(v.x >> 16));
      float f2 = bf2f((unsigned short)(v.y & 0xFFFFu));
      float f3 = bf2f((unsigned short)(v.y >> 16));
      int pk = 0;
      pk = __builtin_amdgcn_cvt_pk_fp8_f32(f0, f1, pk, false);
      pk = __builtin_amdgcn_cvt_pk_fp8_f32(f2, f3, pk, true);
      *(unsigned int*)(out + (size_t)gr * 64 + ch * 4) = (unsigned int)pk;
    }
  }
}

__global__ __launch_bounds__(256) void aggregate(const unsigned char* __restrict__ A8,
                                                 const int* __restrict__ offsets,
                                                 const int* __restrict__ sorted_src,
                                                 const float* __restrict__ dinv,
                                                 const float* __restrict__ bias,
                                                 unsigned short* __restrict__ out, int N) {
  int c = blockIdx.x * 32 + (threadIdx.x >> 3);
  if (c >= N) return;
  int l = threadIdx.x & 7;
  int obase = threadIdx.x & 56;
  int s = offsets[c], e = offsets[c + 1];
  float dc = dinv[c];
  uint2 svr = *(const uint2*)(A8 + ((size_t)c << 6) + l * 8);
  f32x2 a0 = {0.f, 0.f}, a1 = {0.f, 0.f}, a2 = {0.f, 0.f}, a3 = {0.f, 0.f};
  for (int base = s; base < e; base += 16) {
    int i0 = base + l, i1 = base + 8 + l;
    int r0 = (i0 < e) ? __builtin_nontemporal_load(sorted_src + i0) : 0;
    int r1 = (i1 < e) ? __builtin_nontemporal_load(sorted_src + i1) : 0;
    int cnt = e - base; if (cnt > 16) cnt = 16;
    int rj[16];
#pragma unroll
    for (int t = 0; t < 8; ++t)  rj[t] = __shfl(r0, obase + t);
#pragma unroll
    for (int t = 8; t < 16; ++t) rj[t] = __shfl(r1, obase + (t - 8));
#pragma unroll
    for (int t = 0; t < 16; ++t) {
      if (t < cnt) {
        uint2 v = *(const uint2*)(A8 + ((size_t)(unsigned int)rj[t] << 6) + l * 8);
        a0 += __builtin_amdgcn_cvt_pk_f32_fp8((int)v.x, false);
        a1 += __builtin_amdgcn_cvt_pk_f32_fp8((int)v.x, true);
        a2 += __builtin_amdgcn_cvt_pk_f32_fp8((int)v.y, false);
        a3 += __builtin_amdgcn_cvt_pk_f32_fp8((int)v.y, true);
      }
    }
  }
  f32x2 s0 = __builtin_amdgcn_cvt_pk_f32_fp8((int)svr.x, false);
  f32x2 s1 = __builtin_amdgcn_cvt_pk_f32_fp8((int)svr.x, true);
  f32x2 s2 = __builtin_amdgcn_cvt_pk_f32_fp8((int)svr.y, false);
  f32x2 s3 = __builtin_amdgcn_cvt_pk_f32_fp8((int)svr.y, true);
  float acc[8] = {a0[0] + s0[0], a0[1] + s0[1], a1[0] + s1[0], a1[1] + s1[1],
                  a2[0] + s2[0], a2[1] + s2[1], a3[0] + s3[0], a3[1] + s3[1]};
  const float* bp = bias + l * 8;
  short8 ov;
#pragma unroll
  for (int q = 0; q < 8; ++q) {
    float v = fmaf(acc[q], dc, bp[q]);
    ov[q] = (short)f2bf(v > 0.f ? v : 0.f);
  }
  *(short8*)(out + (size_t)c * 64 + l * 8) = ov;
}

__global__ __launch_bounds__(256) void head_loss_kernel(const unsigned short* __restrict__ h,
                                                        const float* __restrict__ lW1,
                                                        const float* __restrict__ lb1,
                                                        const float* __restrict__ lW2,
                                                        const float* __restrict__ lb2,
                                                        const int* __restrict__ labels,
                                                        const float* __restrict__ pmsum,
                                                        float* __restrict__ p,
                                                        float* __restrict__ loss, int N) {
  int n = blockIdx.x * 256 + threadIdx.x;
  float contrib = 0.f;
  if (n < N) {
    float acc[8];
#pragma unroll
    for (int j = 0; j < 8; ++j) acc[j] = lb1[j];
    const unsigned short* hr = h + (size_t)n * 64;
#pragma unroll
    for (int ch = 0; ch < 8; ++ch) {
      short8 hv8 = ((const short8*)hr)[ch];
#pragma unroll
      for (int q = 0; q < 8; ++q) {
        float v = bf2f((unsigned short)hv8[q]);
        int k = ch * 8 + q;
#pragma unroll
        for (int j = 0; j < 8; ++j) acc[j] = fmaf(v, lW1[k * 8 + j], acc[j]);
      }
    }
    float s = lb2[0];
#pragma unroll
    for (int j = 0; j < 8; ++j) {
      float a = acc[j] > 0.f ? acc[j] : 0.f;
      s = fmaf(a, lW2[j], s);
    }
    float pv = 1.0f / (1.0f + expf(-s));
    p[n] = pv;
    float pm = *pmsum / (float)N;
    float y = (float)labels[n];
    float w = y * (1.f - pm) + (1.f - y) * pm;
    float pc = fminf(fmaxf(pv, 1e-7f), 1.f - 1e-7f);
    float bce = -(y * logf(pc) + (1.f - y) * logf(1.f - pc));
    contrib = w * bce / (float)N;
  }
#pragma unroll
  for (int o = 32; o > 0; o >>= 1) contrib += __shfl_down(contrib, o);
  __shared__ float sh[4];
  int lane = threadIdx.x & 63, w = threadIdx.x >> 6;
  if (lane == 0) sh[w] = contrib;
  __syncthreads();
  if (threadIdx.x == 0) atomicAdd(loss, sh[0] + sh[1] + sh[2] + sh[3]);
}

// ---------------- launch ----------------

extern "C" void kernel_launch(void* const* d_in, const int* in_sizes, int n_in,
                              void* d_out, int out_size, void* d_ws, size_t ws_size,
                              hipStream_t stream) {
  const float* x      = (const float*)d_in[0];
  const int*   ei     = (const int*)d_in[1];
  const int*   labels = (const int*)d_in[2];
  const float* W1 = (const float*)d_in[3];
  const float* b1 = (const float*)d_in[4];
  const float* W2 = (const float*)d_in[5];
  const float* b2 = (const float*)d_in[6];
  const float* W3 = (const float*)d_in[7];
  const float* b3 = (const float*)d_in[8];
  const float* lW1 = (const float*)d_in[9];
  const float* lb1 = (const float*)d_in[10];
  const float* lW2 = (const float*)d_in[11];
  const float* lb2 = (const float*)d_in[12];

  int N = in_sizes[2];            // labels: [N,1]
  int E = in_sizes[1] / 2;        // edge_index: [2,E]
  const int* rows = ei;           // sources
  const int* cols = ei + E;       // targets (aggregation)

  int nb = (N + 255) / 256;
  int Npad = (N + 63) & ~63;
  int NCH = (N + 255) >> 8;                 // 256-node chunks (== NBUCK)
  int totalH = NCH * NBLK;                  // fallback histogram entries
  int nb2 = (totalH + 255) / 256;

  // workspace layout (superset for both paths)
  char* ws = (char*)d_ws;
  unsigned char*  A8  = (unsigned char*)ws;                         // Npad*64 fp8
  unsigned short* H   = (unsigned short*)(ws + (size_t)Npad * 64);  // Npad*64 bf16
  unsigned short* Wt1 = H + (size_t)Npad * 64;          // 64*128
  unsigned short* Wt2 = Wt1 + 64 * 128;                 // 64*64
  unsigned short* Wt3 = Wt2 + 64 * 64;                  // 64*64
  float* dinv     = (float*)(Wt3 + 64 * 64);            // N
  int*   offsets  = (int*)(dinv + N);                   // N+1
  int*   deg      = offsets + N + 1;                    // N (mega)
  int*   cur      = deg + N;                            // N (mega)
  int*   partials = cur + N;                            // max(nb2, NCH+1)
  float* labelsum = (float*)(partials + nb2);           // 1024
  float* pmsum    = labelsum + 1024;                    // 1
  int*   histG    = (int*)(pmsum + 1);                  // NBLK*NCH (fallback)
  int*   scanned  = histG + totalH;                     // NBLK*NCH (fallback)
  unsigned int* packed = (unsigned int*)(scanned + totalH);  // E (fallback)
  int*   sorted   = (int*)(packed + E);                 // E

  float* loss = (float*)d_out;
  float* p    = (float*)d_out + 1;

  // ---- try the single cooperative mega-kernel ----
  bool done = false;
  int bpc = 0;
  if (hipOccupancyMaxActiveBlocksPerMultiprocessor(&bpc, (const void*)mega, 256, 0) == hipSuccess
      && bpc > 0) {
    int grid = bpc * 256;             // 256 CUs on MI355X
    if (grid > 1024) grid = 1024;
    if (grid >= NCH + 1 && grid >= 256) {
      MegaParams mp;
      mp.x = x; mp.rows = rows; mp.cols = cols; mp.labels = labels;
      mp.W1 = W1; mp.b1 = b1; mp.W2 = W2; mp.b2 = b2; mp.W3 = W3; mp.b3 = b3;
      mp.lW1 = lW1; mp.lb1 = lb1; mp.lW2 = lW2; mp.lb2 = lb2;
      mp.A8 = A8; mp.H = H; mp.Wt1 = Wt1; mp.Wt2 = Wt2; mp.Wt3 = Wt3;
      mp.dinv = dinv; mp.offsets = offsets; mp.deg = deg; mp.cur = cur;
      mp.sorted = sorted; mp.partials = partials; mp.labelsum = labelsum;
      mp.pmsum = pmsum; mp.p = p; mp.loss = loss;
      mp.N = N; mp.E = E; mp.Npad = Npad; mp.NCH = NCH;
      void* kargs[] = { &mp };
      if (hipLaunchCooperativeKernel((const void*)mega, dim3(grid), dim3(256),
                                     kargs, 0, stream) == hipSuccess)
        done = true;
    }
  }

  if (!done) {
    // ---- fallback: proven round-2 sequence ----
    int gemmBlocks = Npad / 64;
    int aggBlocks  = (N + 31) / 32;
    hist_kernel<<<NBLK, 256, 0, stream>>>(cols, histG, labels, labelsum,
                                          W1, W2, W3, Wt1, Wt2, Wt3, E, N, NCH);
    scan_partials_t<<<nb2, 256, 0, stream>>>(histG, partials, totalH, NCH);
    scan_block<<<1, 256, 0, stream>>>(partials, nb2, loss, labelsum, pmsum);
    scan_final_t<<<nb2, 256, 0, stream>>>(histG, partials, scanned, totalH, NCH);
    scatter_kernel<<<NBLK, 256, 0, stream>>>(rows, cols, scanned, packed, E, NCH);
    csr_finalize<<<NCH, 1024, 0, stream>>>(packed, scanned, sorted, offsets, dinv, N, E, NCH);

    mfma_gemm<128, true><<<gemmBlocks, 256, 0, stream>>>(x, Wt1, dinv, A8, N);
    aggregate<<<aggBlocks, 256, 0, stream>>>(A8, offsets, sorted, dinv, b1, H, N);
    mfma_gemm<64, false><<<gemmBlocks, 256, 0, stream>>>(H, Wt2, dinv, A8, N);
    aggregate<<<aggBlocks, 256, 0, stream>>>(A8, offsets, sorted, dinv, b2, H, N);
    mfma_gemm<64, false><<<gemmBlocks, 256, 0, stream>>>(H, Wt3, dinv, A8, N);
    aggregate<<<aggBlocks, 256, 0, stream>>>(A8, offsets, sorted, dinv, b3, H, N);
    head_loss_kernel<<<nb, 256, 0, stream>>>(H, lW1, lb1, lW2, lb2, labels, pmsum, p, loss, N);
  }
}

// Round 4
// 329.014 us; speedup vs baseline: 3.8878x; 3.8878x over previous
//
#include <hip/hip_runtime.h>
#include <cstdint>
#include <cstddef>

typedef __attribute__((ext_vector_type(8))) short short8;
typedef __attribute__((ext_vector_type(4))) float f32x4;
typedef __attribute__((ext_vector_type(2))) float f32x2;

#define NBLK 512        // edge-chunk blocks for hist/scatter (pow2)
#define NBLK_SHIFT 9

__device__ inline unsigned short f2bf(float f) {
  union { float f; unsigned int u; } x; x.f = f;
  unsigned int r = x.u + 0x7FFFu + ((x.u >> 16) & 1u);  // round-to-nearest-even
  return (unsigned short)(r >> 16);
}
__device__ inline float bf2f(unsigned short s) {
  union { unsigned int u; float f; } x; x.u = ((unsigned int)s) << 16;
  return x.f;
}

// ---------------- P1: per-block bucket histogram (LDS atomics only) ----------------
// blocks 0..2 transpose W1..W3 to bf16 Wt; every block reduces a slice of labels
// into labelsum[block] (summed later by scan_block -> pmsum).

__global__ __launch_bounds__(256) void hist_kernel(const int* __restrict__ cols,
                                                   int* __restrict__ histG,
                                                   const int* __restrict__ labels,
                                                   float* __restrict__ labelsum,
                                                   const float* __restrict__ W1,
                                                   const float* __restrict__ W2,
                                                   const float* __restrict__ W3,
                                                   unsigned short* __restrict__ Wt1,
                                                   unsigned short* __restrict__ Wt2,
                                                   unsigned short* __restrict__ Wt3,
                                                   int E, int N, int NBUCK) {
  __shared__ int h[512];
  if (blockIdx.x < 3) {
    const float* W; unsigned short* Wt; int K;
    if (blockIdx.x == 0)      { W = W1; Wt = Wt1; K = 128; }
    else if (blockIdx.x == 1) { W = W2; Wt = Wt2; K = 64; }
    else                      { W = W3; Wt = Wt3; K = 64; }
    int total = K * 64;
    for (int i = threadIdx.x; i < total; i += 256) {
      int n = i / K, k = i - n * K;  // Wt[n][k] = W[k][n]
      Wt[i] = f2bf(W[k * 64 + n]);
    }
  }
  {
    int chunkL = (N + NBLK - 1) / NBLK;
    int ls = blockIdx.x * chunkL;
    int le = min(N, ls + chunkL);
    float v = 0.f;
    for (int i = ls + threadIdx.x; i < le; i += 256) v += (float)labels[i];
#pragma unroll
    for (int o = 32; o > 0; o >>= 1) v += __shfl_down(v, o);
    __shared__ float sl[4];
    if ((threadIdx.x & 63) == 0) sl[threadIdx.x >> 6] = v;
    __syncthreads();
    if (threadIdx.x == 0) labelsum[blockIdx.x] = sl[0] + sl[1] + sl[2] + sl[3];
  }
  for (int i = threadIdx.x; i < NBUCK; i += 256) h[i] = 0;
  __syncthreads();
  int chunk = (E + NBLK - 1) / NBLK;
  int s = blockIdx.x * chunk;
  int e = min(E, s + chunk);
  for (int i = s + threadIdx.x; i < e; i += 256) atomicAdd(&h[cols[i] >> 8], 1);
  __syncthreads();
  for (int i = threadIdx.x; i < NBUCK; i += 256)
    histG[blockIdx.x * NBUCK + i] = h[i];
}

// ---------------- P2: scan of NBUCK*NBLK counts, bucket-major logical order ----------------

__global__ __launch_bounds__(256) void scan_partials_t(const int* __restrict__ histG,
                                                       int* __restrict__ partials,
                                                       int total, int NBUCK) {
  int i = blockIdx.x * 256 + threadIdx.x;
  int v = 0;
  if (i < total) {
    int bucket = i >> NBLK_SHIFT, blk = i & (NBLK - 1);
    v = histG[blk * NBUCK + bucket];
  }
#pragma unroll
  for (int o = 32; o > 0; o >>= 1) v += __shfl_down(v, o);
  __shared__ int s[4];
  if ((threadIdx.x & 63) == 0) s[threadIdx.x >> 6] = v;
  __syncthreads();
  if (threadIdx.x == 0) partials[blockIdx.x] = s[0] + s[1] + s[2] + s[3];
}

__global__ __launch_bounds__(256) void scan_block(int* __restrict__ partials, int nb,
                                                  float* __restrict__ loss,
                                                  const float* __restrict__ labelsum,
                                                  float* __restrict__ pmsum) {
  __shared__ int tmp[256];
  __shared__ int carry;
  int tid = threadIdx.x;
  {
    float v = 0.f;
    for (int i = tid; i < NBLK; i += 256) v += labelsum[i];
#pragma unroll
    for (int o = 32; o > 0; o >>= 1) v += __shfl_down(v, o);
    __shared__ float sl[4];
    if ((tid & 63) == 0) sl[tid >> 6] = v;
    __syncthreads();
    if (tid == 0) *pmsum = sl[0] + sl[1] + sl[2] + sl[3];
  }
  if (tid == 0) { carry = 0; *loss = 0.f; }
  __syncthreads();
  for (int base = 0; base < nb; base += 256) {
    int i = base + tid;
    int v = (i < nb) ? partials[i] : 0;
    tmp[tid] = v;
    __syncthreads();
    int incl = v;
    for (int o = 1; o < 256; o <<= 1) {
      int t = (tid >= o) ? tmp[tid - o] : 0;
      __syncthreads();
      incl += t;
      tmp[tid] = incl;
      __syncthreads();
    }
    int total = tmp[255];
    int c = carry;
    if (i < nb) partials[i] = c + incl - v;  // exclusive
    __syncthreads();
    if (tid == 0) carry = c + total;
    __syncthreads();
  }
}

__global__ __launch_bounds__(256) void scan_final_t(const int* __restrict__ histG,
                                                    const int* __restrict__ partials,
                                                    int* __restrict__ scannedG,
                                                    int total, int NBUCK) {
  __shared__ int tmp[256];
  int tid = threadIdx.x;
  int i = blockIdx.x * 256 + tid;
  int bucket = i >> NBLK_SHIFT, blk = i & (NBLK - 1);
  int v = (i < total) ? histG[blk * NBUCK + bucket] : 0;
  tmp[tid] = v;
  __syncthreads();
  int incl = v;
  for (int o = 1; o < 256; o <<= 1) {
    int t = (tid >= o) ? tmp[tid - o] : 0;
    __syncthreads();
    incl += t;
    tmp[tid] = incl;
    __syncthreads();
  }
  if (i < total) scannedG[blk * NBUCK + bucket] = partials[blockIdx.x] + incl - v;
}

// ---------------- P3: bucket-partition scatter (LDS cursors, no global atomics) ----------------

__global__ __launch_bounds__(256) void scatter_kernel(const int* __restrict__ rows,
                                                      const int* __restrict__ cols,
                                                      const int* __restrict__ scannedG,
                                                      unsigned int* __restrict__ packed,
                                                      int E, int NBUCK) {
  __shared__ int cur[512];
  for (int i = threadIdx.x; i < NBUCK; i += 256)
    cur[i] = scannedG[blockIdx.x * NBUCK + i];
  __syncthreads();
  int chunk = (E + NBLK - 1) / NBLK;
  int s = blockIdx.x * chunk;
  int e = min(E, s + chunk);
  for (int i = s + threadIdx.x; i < e; i += 256) {
    int c = cols[i];
    int r = rows[i];
    int pos = atomicAdd(&cur[c >> 8], 1);
    packed[pos] = ((unsigned int)(c & 255) << 24) | (unsigned int)r;
  }
}

// ---------------- P4: per-bucket CSR finalize (1024 threads/block) ----------------

__global__ __launch_bounds__(1024) void csr_finalize(const unsigned int* __restrict__ packed,
                                                     const int* __restrict__ scannedG,
                                                     int* __restrict__ sorted_src,
                                                     int* __restrict__ offsets,
                                                     float* __restrict__ dinv,
                                                     int N, int E, int NBUCK) {
  __shared__ int h[256];
  __shared__ int tmp[256];
  __shared__ int cur[256];
  int b = blockIdx.x;
  int tid = threadIdx.x;
  int base = scannedG[b];
  int end = (b + 1 < NBUCK) ? scannedG[b + 1] : E;
  if (tid < 256) h[tid] = 0;
  __syncthreads();
  for (int i = base + tid; i < end; i += 1024)
    atomicAdd(&h[packed[i] >> 24], 1);
  __syncthreads();
  if (tid < 256) {
    int v = h[tid];
    tmp[tid] = v;
  }
  __syncthreads();
  if (tid < 256) {
    int v = h[tid];
    int incl = v;
    for (int o = 1; o < 256; o <<= 1) {
      int t = (tid >= o) ? tmp[tid - o] : 0;
      __syncthreads();
      incl += t;
      tmp[tid] = incl;
      __syncthreads();
    }
    int excl = incl - v;
    int node = b * 256 + tid;
    if (node < N) {
      offsets[node] = base + excl;
      dinv[node] = rsqrtf((float)(v + 1));  // +1 self loop
    }
    cur[tid] = base + excl;
    if (b == NBUCK - 1 && tid == 0) offsets[N] = E;
  } else {
    for (int o = 1; o < 256; o <<= 1) { __syncthreads(); __syncthreads(); }
  }
  __syncthreads();
  for (int i = base + tid; i < end; i += 1024) {
    unsigned int p = packed[i];
    int pos = atomicAdd(&cur[p >> 24], 1);
    sorted_src[pos] = (int)(p & 0xFFFFFFu);
  }
}

// ---------------- MFMA GEMM (layer 1 only): A_fp8[N,64] = (x[N,128] @ W1) * dinv[n] ----------------

__global__ __launch_bounds__(256) void mfma_gemm1(const float* __restrict__ xv,
                                                  const unsigned short* __restrict__ Wt,
                                                  const float* __restrict__ dinv,
                                                  unsigned char* __restrict__ out, int N) {
  const int K = 128;
  __shared__ unsigned short tile[4][16 * 68];
  int w = threadIdx.x >> 6, lane = threadIdx.x & 63;
  int m = lane & 15, quad = lane >> 4;
  int m0 = blockIdx.x * 64 + w * 16;
  int rowA = m0 + m;
  bool rowOK = rowA < N;
  f32x4 acc[4] = {{0.f,0.f,0.f,0.f},{0.f,0.f,0.f,0.f},{0.f,0.f,0.f,0.f},{0.f,0.f,0.f,0.f}};
#pragma unroll
  for (int kc = 0; kc < K / 32; ++kc) {
    short8 a = {0, 0, 0, 0, 0, 0, 0, 0};
    if (rowOK) {
      const float* hp = xv + (size_t)rowA * K + kc * 32 + quad * 8;
      float4 p0 = ((const float4*)hp)[0];
      float4 p1 = ((const float4*)hp)[1];
      a[0] = (short)f2bf(p0.x); a[1] = (short)f2bf(p0.y);
      a[2] = (short)f2bf(p0.z); a[3] = (short)f2bf(p0.w);
      a[4] = (short)f2bf(p1.x); a[5] = (short)f2bf(p1.y);
      a[6] = (short)f2bf(p1.z); a[7] = (short)f2bf(p1.w);
    }
#pragma unroll
    for (int t = 0; t < 4; ++t) {
      short8 b = *(const short8*)(Wt + (size_t)(t * 16 + m) * K + kc * 32 + quad * 8);
      acc[t] = __builtin_amdgcn_mfma_f32_16x16x32_bf16(a, b, acc[t], 0, 0, 0);
    }
  }
  unsigned short* tw = tile[w];
#pragma unroll
  for (int r = 0; r < 4; ++r) {
    int row = quad * 4 + r;
    int gr = m0 + row;
    float dv = dinv[gr < N ? gr : 0];
#pragma unroll
    for (int t = 0; t < 4; ++t)
      tw[row * 68 + t * 16 + m] = f2bf(acc[t][r] * dv);
  }
#pragma unroll
  for (int p = 0; p < 4; ++p) {
    int row = p * 4 + (lane >> 4);
    int ch = lane & 15;  // 4-feature chunk
    int gr = m0 + row;
    if (gr < N) {
      uint2 v = *(const uint2*)(tw + row * 68 + ch * 4);
      float f0 = bf2f((unsigned short)(v.x & 0xFFFFu));
      float f1 = bf2f((unsigned short)(v.x >> 16));
      float f2 = bf2f((unsigned short)(v.y & 0xFFFFu));
      float f3 = bf2f((unsigned short)(v.y >> 16));
      int pk = 0;
      pk = __builtin_amdgcn_cvt_pk_fp8_f32(f0, f1, pk, false);
      pk = __builtin_amdgcn_cvt_pk_fp8_f32(f2, f3, pk, true);
      *(unsigned int*)(out + (size_t)gr * 64 + ch * 4) = (unsigned int)pk;
    }
  }
}

// ---------------- FUSED: gather-aggregate + bias + ReLU + (h @ Wnext)*dinv -> A8out ----------------
// Octet gather layout (proven): one node per 8-lane octet, lane owns one 8B chunk,
// 16 gathers in flight. h rows staged in LDS (32x68 bf16), 16 MFMAs per block,
// fp8 pack epilogue. H never touches global memory.

__global__ __launch_bounds__(256) void agg_gemm(const unsigned char* __restrict__ A8in,
                                                const int* __restrict__ offsets,
                                                const int* __restrict__ sorted_src,
                                                const float* __restrict__ dinv,
                                                const float* __restrict__ bias,
                                                const unsigned short* __restrict__ Wt,
                                                unsigned char* __restrict__ A8out, int N) {
  __shared__ unsigned short hl[32 * 68];
  int cl = threadIdx.x >> 3;             // local node 0..31
  int c = blockIdx.x * 32 + cl;
  int l = threadIdx.x & 7;               // 8B chunk of the 64B row
  int obase = threadIdx.x & 56;
  bool ok = c < N;
  int s = 0, e = 0;
  float dc = 0.f;
  uint2 svr = {0u, 0u};
  if (ok) {
    s = offsets[c]; e = offsets[c + 1];
    dc = dinv[c];
    svr = *(const uint2*)(A8in + ((size_t)c << 6) + l * 8);
  }
  f32x2 a0 = {0.f, 0.f}, a1 = {0.f, 0.f}, a2 = {0.f, 0.f}, a3 = {0.f, 0.f};
  for (int base = s; base < e; base += 16) {
    int i0 = base + l, i1 = base + 8 + l;
    int r0 = (i0 < e) ? __builtin_nontemporal_load(sorted_src + i0) : 0;
    int r1 = (i1 < e) ? __builtin_nontemporal_load(sorted_src + i1) : 0;
    int cnt = e - base; if (cnt > 16) cnt = 16;
    int rj[16];
#pragma unroll
    for (int t = 0; t < 8; ++t)  rj[t] = __shfl(r0, obase + t);
#pragma unroll
    for (int t = 8; t < 16; ++t) rj[t] = __shfl(r1, obase + (t - 8));
#pragma unroll
    for (int t = 0; t < 16; ++t) {
      if (t < cnt) {
        uint2 v = *(const uint2*)(A8in + ((size_t)(unsigned int)rj[t] << 6) + l * 8);
        a0 += __builtin_amdgcn_cvt_pk_f32_fp8((int)v.x, false);
        a1 += __builtin_amdgcn_cvt_pk_f32_fp8((int)v.x, true);
        a2 += __builtin_amdgcn_cvt_pk_f32_fp8((int)v.y, false);
        a3 += __builtin_amdgcn_cvt_pk_f32_fp8((int)v.y, true);
      }
    }
  }
  // h = relu(agg*dc + b) -> bf16 LDS row (zeros for invalid rows)
  {
    f32x2 s0 = __builtin_amdgcn_cvt_pk_f32_fp8((int)svr.x, false);
    f32x2 s1 = __builtin_amdgcn_cvt_pk_f32_fp8((int)svr.x, true);
    f32x2 s2 = __builtin_amdgcn_cvt_pk_f32_fp8((int)svr.y, false);
    f32x2 s3 = __builtin_amdgcn_cvt_pk_f32_fp8((int)svr.y, true);
    float acc[8] = {a0[0] + s0[0], a0[1] + s0[1], a1[0] + s1[0], a1[1] + s1[1],
                    a2[0] + s2[0], a2[1] + s2[1], a3[0] + s3[0], a3[1] + s3[1]};
    const float* bp = bias + l * 8;
    unsigned int w0 = 0, w1 = 0, w2 = 0, w3 = 0;
    if (ok) {
      unsigned short hv[8];
#pragma unroll
      for (int q = 0; q < 8; ++q) {
        float v = fmaf(acc[q], dc, bp[q]);
        hv[q] = f2bf(v > 0.f ? v : 0.f);
      }
      w0 = (unsigned int)hv[0] | ((unsigned int)hv[1] << 16);
      w1 = (unsigned int)hv[2] | ((unsigned int)hv[3] << 16);
      w2 = (unsigned int)hv[4] | ((unsigned int)hv[5] << 16);
      w3 = (unsigned int)hv[6] | ((unsigned int)hv[7] << 16);
    }
    unsigned int* dst = (unsigned int*)(hl + cl * 68 + l * 8);
    dst[0] = w0; dst[1] = w1; dst[2] = w2; dst[3] = w3;
  }
  __syncthreads();
  // MFMA: wave wv: rows (wv&1)*16..+15, cols (wv>>1)*32..+31, K=64
  int wv = threadIdx.x >> 6, lane = threadIdx.x & 63;
  int m = lane & 15, quad = lane >> 4;
  int rbase = (wv & 1) * 16, cbase = (wv >> 1) * 32;
  f32x4 acc2[2] = {{0.f,0.f,0.f,0.f},{0.f,0.f,0.f,0.f}};
#pragma unroll
  for (int kc = 0; kc < 2; ++kc) {
    union { uint2 u[2]; short8 s8; } av;
    const unsigned int* ap = (const unsigned int*)(hl + (rbase + m) * 68 + kc * 32 + quad * 8);
    av.u[0] = ((const uint2*)ap)[0];
    av.u[1] = ((const uint2*)ap)[1];
#pragma unroll
    for (int t = 0; t < 2; ++t) {
      short8 b = *(const short8*)(Wt + (size_t)(cbase + t * 16 + m) * 64 + kc * 32 + quad * 8);
      acc2[t] = __builtin_amdgcn_mfma_f32_16x16x32_bf16(av.s8, b, acc2[t], 0, 0, 0);
    }
  }
  __syncthreads();   // all reads of hl done; reuse as output tile
#pragma unroll
  for (int r = 0; r < 4; ++r) {
    int row = rbase + quad * 4 + r;
    int gr = blockIdx.x * 32 + row;
    float dv = dinv[gr < N ? gr : 0];
#pragma unroll
    for (int t = 0; t < 2; ++t)
      hl[row * 68 + cbase + t * 16 + m] = f2bf(acc2[t][r] * dv);
  }
  __syncthreads();
  // fp8 pack: 512 (row, 4-feat-chunk) items over 256 threads
#pragma unroll
  for (int u = 0; u < 2; ++u) {
    int id = threadIdx.x * 2 + u;
    int row = id >> 4, ch = id & 15;
    int gr = blockIdx.x * 32 + row;
    if (gr < N) {
      uint2 v = *(const uint2*)(hl + row * 68 + ch * 4);
      float f0 = bf2f((unsigned short)(v.x & 0xFFFFu));
      float f1 = bf2f((unsigned short)(v.x >> 16));
      float f2 = bf2f((unsigned short)(v.y & 0xFFFFu));
      float f3 = bf2f((unsigned short)(v.y >> 16));
      int pk = 0;
      pk = __builtin_amdgcn_cvt_pk_fp8_f32(f0, f1, pk, false);
      pk = __builtin_amdgcn_cvt_pk_fp8_f32(f2, f3, pk, true);
      *(unsigned int*)(A8out + (size_t)gr * 64 + ch * 4) = (unsigned int)pk;
    }
  }
}

// ---------------- FUSED: gather-aggregate (layer 3) + MLP head + sigmoid + BCE ----------------

__global__ __launch_bounds__(256) void agg_head(const unsigned char* __restrict__ A8in,
                                                const int* __restrict__ offsets,
                                                const int* __restrict__ sorted_src,
                                                const float* __restrict__ dinv,
                                                const float* __restrict__ bias,
                                                const float* __restrict__ lW1,
                                                const float* __restrict__ lb1,
                                                const float* __restrict__ lW2,
                                                const float* __restrict__ lb2,
                                                const int* __restrict__ labels,
                                                const float* __restrict__ pmsum,
                                                float* __restrict__ p,
                                                float* __restrict__ loss, int N) {
  int cl = threadIdx.x >> 3;
  int c = blockIdx.x * 32 + cl;
  int l = threadIdx.x & 7;
  int obase = threadIdx.x & 56;
  bool ok = c < N;
  int s = 0, e = 0;
  float dc = 0.f;
  uint2 svr = {0u, 0u};
  if (ok) {
    s = offsets[c]; e = offsets[c + 1];
    dc = dinv[c];
    svr = *(const uint2*)(A8in + ((size_t)c << 6) + l * 8);
  }
  f32x2 a0 = {0.f, 0.f}, a1 = {0.f, 0.f}, a2 = {0.f, 0.f}, a3 = {0.f, 0.f};
  for (int base = s; base < e; base += 16) {
    int i0 = base + l, i1 = base + 8 + l;
    int r0 = (i0 < e) ? __builtin_nontemporal_load(sorted_src + i0) : 0;
    int r1 = (i1 < e) ? __builtin_nontemporal_load(sorted_src + i1) : 0;
    int cnt = e - base; if (cnt > 16) cnt = 16;
    int rj[16];
#pragma unroll
    for (int t = 0; t < 8; ++t)  rj[t] = __shfl(r0, obase + t);
#pragma unroll
    for (int t = 8; t < 16; ++t) rj[t] = __shfl(r1, obase + (t - 8));
#pragma unroll
    for (int t = 0; t < 16; ++t) {
      if (t < cnt) {
        uint2 v = *(const uint2*)(A8in + ((size_t)(unsigned int)rj[t] << 6) + l * 8);
        a0 += __builtin_amdgcn_cvt_pk_f32_fp8((int)v.x, false);
        a1 += __builtin_amdgcn_cvt_pk_f32_fp8((int)v.x, true);
        a2 += __builtin_amdgcn_cvt_pk_f32_fp8((int)v.y, false);
        a3 += __builtin_amdgcn_cvt_pk_f32_fp8((int)v.y, true);
      }
    }
  }
  float contrib = 0.f;
  {
    f32x2 s0 = __builtin_amdgcn_cvt_pk_f32_fp8((int)svr.x, false);
    f32x2 s1 = __builtin_amdgcn_cvt_pk_f32_fp8((int)svr.x, true);
    f32x2 s2 = __builtin_amdgcn_cvt_pk_f32_fp8((int)svr.y, false);
    f32x2 s3 = __builtin_amdgcn_cvt_pk_f32_fp8((int)svr.y, true);
    float acc[8] = {a0[0] + s0[0], a0[1] + s0[1], a1[0] + s1[0], a1[1] + s1[1],
                    a2[0] + s2[0], a2[1] + s2[1], a3[0] + s3[0], a3[1] + s3[1]};
    const float* bp = bias + l * 8;
    float hq[8];
#pragma unroll
    for (int q = 0; q < 8; ++q) {
      float v = fmaf(acc[q], dc, bp[q]);
      hq[q] = v > 0.f ? v : 0.f;
    }
    // per-lane partial contraction: acc8[j] = sum over this lane's 8 feats
    float acc8[8] = {0.f,0.f,0.f,0.f,0.f,0.f,0.f,0.f};
#pragma unroll
    for (int q = 0; q < 8; ++q) {
      int k = l * 8 + q;
#pragma unroll
      for (int j = 0; j < 8; ++j) acc8[j] = fmaf(hq[q], lW1[k * 8 + j], acc8[j]);
    }
    // octet reduce (lanes l^1, l^2, l^4 are in the same octet)
#pragma unroll
    for (int j = 0; j < 8; ++j) {
      acc8[j] += __shfl_xor(acc8[j], 1);
      acc8[j] += __shfl_xor(acc8[j], 2);
      acc8[j] += __shfl_xor(acc8[j], 4);
    }
    if (ok && l == 0) {
      float sv = lb2[0];
#pragma unroll
      for (int j = 0; j < 8; ++j) {
        float a = acc8[j] + lb1[j];
        a = a > 0.f ? a : 0.f;
        sv = fmaf(a, lW2[j], sv);
      }
      float pv = 1.0f / (1.0f + expf(-sv));
      p[c] = pv;
      float pm = *pmsum / (float)N;
      float y = (float)labels[c];
      float w = y * (1.f - pm) + (1.f - y) * pm;
      float pc = fminf(fmaxf(pv, 1e-7f), 1.f - 1e-7f);
      float bce = -(y * logf(pc) + (1.f - y) * logf(1.f - pc));
      contrib = w * bce / (float)N;
    }
  }
#pragma unroll
  for (int o = 32; o > 0; o >>= 1) contrib += __shfl_down(contrib, o);
  __shared__ float sh[4];
  int lane = threadIdx.x & 63, wv = threadIdx.x >> 6;
  if (lane == 0) sh[wv] = contrib;
  __syncthreads();
  if (threadIdx.x == 0) atomicAdd(loss, sh[0] + sh[1] + sh[2] + sh[3]);
}

// ---------------- launch ----------------

extern "C" void kernel_launch(void* const* d_in, const int* in_sizes, int n_in,
                              void* d_out, int out_size, void* d_ws, size_t ws_size,
                              hipStream_t stream) {
  const float* x      = (const float*)d_in[0];
  const int*   ei     = (const int*)d_in[1];
  const int*   labels = (const int*)d_in[2];
  const float* W1 = (const float*)d_in[3];
  const float* b1 = (const float*)d_in[4];
  const float* W2 = (const float*)d_in[5];
  const float* b2 = (const float*)d_in[6];
  const float* W3 = (const float*)d_in[7];
  const float* b3 = (const float*)d_in[8];
  const float* lW1 = (const float*)d_in[9];
  const float* lb1 = (const float*)d_in[10];
  const float* lW2 = (const float*)d_in[11];
  const float* lb2 = (const float*)d_in[12];

  int N = in_sizes[2];            // labels: [N,1]
  int E = in_sizes[1] / 2;        // edge_index: [2,E]
  const int* rows = ei;           // sources
  const int* cols = ei + E;       // targets (aggregation)

  int Npad = (N + 63) & ~63;
  int NBUCK = (N + 255) >> 8;               // 256-node buckets
  int totalH = NBUCK * NBLK;                // histogram entries
  int nb2 = (totalH + 255) / 256;

  // workspace layout (same footprint as the proven round-2 version; A8b lives
  // in the first half of the old H region)
  char* ws = (char*)d_ws;
  unsigned char*  A8a = (unsigned char*)ws;                         // Npad*64 fp8
  unsigned char*  A8b = (unsigned char*)(ws + (size_t)Npad * 64);   // Npad*64 fp8
  unsigned short* Wt1 = (unsigned short*)(ws + (size_t)Npad * 192); // 64*128
  unsigned short* Wt2 = Wt1 + 64 * 128;                 // 64*64
  unsigned short* Wt3 = Wt2 + 64 * 64;                  // 64*64
  float* dinv     = (float*)(Wt3 + 64 * 64);            // N
  int*   offsets  = (int*)(dinv + N);                   // N+1
  int*   histG    = offsets + N + 1;                    // NBLK*NBUCK
  int*   scanned  = histG + totalH;                     // NBLK*NBUCK
  unsigned int* packed = (unsigned int*)(scanned + totalH);  // E
  int*   sorted   = (int*)(packed + E);                 // E
  int*   partials = sorted + E;                         // nb2
  float* pmsum    = (float*)(partials + nb2);           // 1
  float* labelsum = pmsum + 1;                          // NBLK

  float* loss = (float*)d_out;
  float* p    = (float*)d_out + 1;

  int gemmBlocks = Npad / 64;
  int aggBlocks  = (N + 31) / 32;

  // ---- atomic-free CSR build (+ Wt transpose & label-sum folded into hist) ----
  hist_kernel<<<NBLK, 256, 0, stream>>>(cols, histG, labels, labelsum,
                                        W1, W2, W3, Wt1, Wt2, Wt3, E, N, NBUCK);
  scan_partials_t<<<nb2, 256, 0, stream>>>(histG, partials, totalH, NBUCK);
  scan_block<<<1, 256, 0, stream>>>(partials, nb2, loss, labelsum, pmsum);
  scan_final_t<<<nb2, 256, 0, stream>>>(histG, partials, scanned, totalH, NBUCK);
  scatter_kernel<<<NBLK, 256, 0, stream>>>(rows, cols, scanned, packed, E, NBUCK);
  csr_finalize<<<NBUCK, 1024, 0, stream>>>(packed, scanned, sorted, offsets, dinv, N, E, NBUCK);

  // ---- layer 1 GEMM (K=128, fp32 x converted in-flight) ----
  mfma_gemm1<<<gemmBlocks, 256, 0, stream>>>(x, Wt1, dinv, A8a, N);

  // ---- fused layers: agg1+gemm2, agg2+gemm3, agg3+head ----
  agg_gemm<<<aggBlocks, 256, 0, stream>>>(A8a, offsets, sorted, dinv, b1, Wt2, A8b, N);
  agg_gemm<<<aggBlocks, 256, 0, stream>>>(A8b, offsets, sorted, dinv, b2, Wt3, A8a, N);
  agg_head<<<aggBlocks, 256, 0, stream>>>(A8a, offsets, sorted, dinv, b3,
                                          lW1, lb1, lW2, lb2, labels, pmsum, p, loss, N);
}

// Round 6
// 305.983 us; speedup vs baseline: 4.1804x; 1.0753x over previous
//
#include <hip/hip_runtime.h>
#include <cstdint>
#include <cstddef>

typedef __attribute__((ext_vector_type(8))) short short8;
typedef __attribute__((ext_vector_type(4))) float f32x4;
typedef __attribute__((ext_vector_type(2))) float f32x2;

#define NBLK 512        // edge-chunk blocks for hist/scatter (pow2)
#define NBLK_SHIFT 9

__device__ inline unsigned short f2bf(float f) {
  union { float f; unsigned int u; } x; x.f = f;
  unsigned int r = x.u + 0x7FFFu + ((x.u >> 16) & 1u);  // round-to-nearest-even
  return (unsigned short)(r >> 16);
}
__device__ inline float bf2f(unsigned short s) {
  union { unsigned int u; float f; } x; x.u = ((unsigned int)s) << 16;
  return x.f;
}

// ---------------- P1: per-block bucket histogram (LDS atomics only) ----------------

__global__ __launch_bounds__(256) void hist_kernel(const int* __restrict__ cols,
                                                   int* __restrict__ histG,
                                                   const int* __restrict__ labels,
                                                   float* __restrict__ labelsum,
                                                   const float* __restrict__ W1,
                                                   const float* __restrict__ W2,
                                                   const float* __restrict__ W3,
                                                   unsigned short* __restrict__ Wt1,
                                                   unsigned short* __restrict__ Wt2,
                                                   unsigned short* __restrict__ Wt3,
                                                   int E, int N, int NBUCK) {
  __shared__ int h[512];
  if (blockIdx.x < 3) {
    const float* W; unsigned short* Wt; int K;
    if (blockIdx.x == 0)      { W = W1; Wt = Wt1; K = 128; }
    else if (blockIdx.x == 1) { W = W2; Wt = Wt2; K = 64; }
    else                      { W = W3; Wt = Wt3; K = 64; }
    int total = K * 64;
    for (int i = threadIdx.x; i < total; i += 256) {
      int n = i / K, k = i - n * K;  // Wt[n][k] = W[k][n]
      Wt[i] = f2bf(W[k * 64 + n]);
    }
  }
  {
    int chunkL = (N + NBLK - 1) / NBLK;
    int ls = blockIdx.x * chunkL;
    int le = min(N, ls + chunkL);
    float v = 0.f;
    for (int i = ls + threadIdx.x; i < le; i += 256) v += (float)labels[i];
#pragma unroll
    for (int o = 32; o > 0; o >>= 1) v += __shfl_down(v, o);
    __shared__ float sl[4];
    if ((threadIdx.x & 63) == 0) sl[threadIdx.x >> 6] = v;
    __syncthreads();
    if (threadIdx.x == 0) labelsum[blockIdx.x] = sl[0] + sl[1] + sl[2] + sl[3];
  }
  for (int i = threadIdx.x; i < NBUCK; i += 256) h[i] = 0;
  __syncthreads();
  int chunk = (E + NBLK - 1) / NBLK;
  int s = blockIdx.x * chunk;
  int e = min(E, s + chunk);
  for (int i = s + threadIdx.x; i < e; i += 256) atomicAdd(&h[cols[i] >> 8], 1);
  __syncthreads();
  for (int i = threadIdx.x; i < NBUCK; i += 256)
    histG[blockIdx.x * NBUCK + i] = h[i];
}

// ---------------- P2: scan of NBUCK*NBLK counts, bucket-major logical order ----------------

__global__ __launch_bounds__(256) void scan_partials_t(const int* __restrict__ histG,
                                                       int* __restrict__ partials,
                                                       int total, int NBUCK) {
  int i = blockIdx.x * 256 + threadIdx.x;
  int v = 0;
  if (i < total) {
    int bucket = i >> NBLK_SHIFT, blk = i & (NBLK - 1);
    v = histG[blk * NBUCK + bucket];
  }
#pragma unroll
  for (int o = 32; o > 0; o >>= 1) v += __shfl_down(v, o);
  __shared__ int s[4];
  if ((threadIdx.x & 63) == 0) s[threadIdx.x >> 6] = v;
  __syncthreads();
  if (threadIdx.x == 0) partials[blockIdx.x] = s[0] + s[1] + s[2] + s[3];
}

__global__ __launch_bounds__(256) void scan_block(int* __restrict__ partials, int nb,
                                                  float* __restrict__ loss,
                                                  const float* __restrict__ labelsum,
                                                  float* __restrict__ pmsum) {
  __shared__ int tmp[256];
  __shared__ int carry;
  int tid = threadIdx.x;
  {
    float v = 0.f;
    for (int i = tid; i < NBLK; i += 256) v += labelsum[i];
#pragma unroll
    for (int o = 32; o > 0; o >>= 1) v += __shfl_down(v, o);
    __shared__ float sl[4];
    if ((tid & 63) == 0) sl[tid >> 6] = v;
    __syncthreads();
    if (tid == 0) *pmsum = sl[0] + sl[1] + sl[2] + sl[3];
  }
  if (tid == 0) { carry = 0; *loss = 0.f; }
  __syncthreads();
  for (int base = 0; base < nb; base += 256) {
    int i = base + tid;
    int v = (i < nb) ? partials[i] : 0;
    tmp[tid] = v;
    __syncthreads();
    int incl = v;
    for (int o = 1; o < 256; o <<= 1) {
      int t = (tid >= o) ? tmp[tid - o] : 0;
      __syncthreads();
      incl += t;
      tmp[tid] = incl;
      __syncthreads();
    }
    int total = tmp[255];
    int c = carry;
    if (i < nb) partials[i] = c + incl - v;  // exclusive
    __syncthreads();
    if (tid == 0) carry = c + total;
    __syncthreads();
  }
}

__global__ __launch_bounds__(256) void scan_final_t(const int* __restrict__ histG,
                                                    const int* __restrict__ partials,
                                                    int* __restrict__ scannedG,
                                                    int total, int NBUCK) {
  __shared__ int tmp[256];
  int tid = threadIdx.x;
  int i = blockIdx.x * 256 + tid;
  int bucket = i >> NBLK_SHIFT, blk = i & (NBLK - 1);
  int v = (i < total) ? histG[blk * NBUCK + bucket] : 0;
  tmp[tid] = v;
  __syncthreads();
  int incl = v;
  for (int o = 1; o < 256; o <<= 1) {
    int t = (tid >= o) ? tmp[tid - o] : 0;
    __syncthreads();
    incl += t;
    tmp[tid] = incl;
    __syncthreads();
  }
  if (i < total) scannedG[blk * NBUCK + bucket] = partials[blockIdx.x] + incl - v;
}

// ---------------- P3: bucket-partition scatter (LDS cursors, no global atomics) ----------------

__global__ __launch_bounds__(256) void scatter_kernel(const int* __restrict__ rows,
                                                      const int* __restrict__ cols,
                                                      const int* __restrict__ scannedG,
                                                      unsigned int* __restrict__ packed,
                                                      int E, int NBUCK) {
  __shared__ int cur[512];
  for (int i = threadIdx.x; i < NBUCK; i += 256)
    cur[i] = scannedG[blockIdx.x * NBUCK + i];
  __syncthreads();
  int chunk = (E + NBLK - 1) / NBLK;
  int s = blockIdx.x * chunk;
  int e = min(E, s + chunk);
  for (int i = s + threadIdx.x; i < e; i += 256) {
    int c = cols[i];
    int r = rows[i];
    int pos = atomicAdd(&cur[c >> 8], 1);
    packed[pos] = ((unsigned int)(c & 255) << 24) | (unsigned int)r;
  }
}

// ---------------- P4: per-bucket CSR finalize (1024 threads/block) ----------------

__global__ __launch_bounds__(1024) void csr_finalize(const unsigned int* __restrict__ packed,
                                                     const int* __restrict__ scannedG,
                                                     int* __restrict__ sorted_src,
                                                     int* __restrict__ offsets,
                                                     float* __restrict__ dinv,
                                                     int N, int E, int NBUCK) {
  __shared__ int h[256];
  __shared__ int tmp[256];
  __shared__ int cur[256];
  int b = blockIdx.x;
  int tid = threadIdx.x;
  int base = scannedG[b];
  int end = (b + 1 < NBUCK) ? scannedG[b + 1] : E;
  if (tid < 256) h[tid] = 0;
  __syncthreads();
  for (int i = base + tid; i < end; i += 1024)
    atomicAdd(&h[packed[i] >> 24], 1);
  __syncthreads();
  if (tid < 256) {
    int v = h[tid];
    tmp[tid] = v;
  }
  __syncthreads();
  if (tid < 256) {
    int v = h[tid];
    int incl = v;
    for (int o = 1; o < 256; o <<= 1) {
      int t = (tid >= o) ? tmp[tid - o] : 0;
      __syncthreads();
      incl += t;
      tmp[tid] = incl;
      __syncthreads();
    }
    int excl = incl - v;
    int node = b * 256 + tid;
    if (node < N) {
      offsets[node] = base + excl;
      dinv[node] = rsqrtf((float)(v + 1));  // +1 self loop
    }
    cur[tid] = base + excl;
    if (b == NBUCK - 1 && tid == 0) offsets[N] = E;
  } else {
    for (int o = 1; o < 256; o <<= 1) { __syncthreads(); __syncthreads(); }
  }
  __syncthreads();
  for (int i = base + tid; i < end; i += 1024) {
    unsigned int p = packed[i];
    int pos = atomicAdd(&cur[p >> 24], 1);
    sorted_src[pos] = (int)(p & 0xFFFFFFu);
  }
}

// ---------------- MFMA GEMM (layer 1 only): A_fp8[N,64] = (x[N,128] @ W1) * dinv[n] ----------------

__global__ __launch_bounds__(256) void mfma_gemm1(const float* __restrict__ xv,
                                                  const unsigned short* __restrict__ Wt,
                                                  const float* __restrict__ dinv,
                                                  unsigned char* __restrict__ out, int N) {
  const int K = 128;
  __shared__ unsigned short tile[4][16 * 68];
  int w = threadIdx.x >> 6, lane = threadIdx.x & 63;
  int m = lane & 15, quad = lane >> 4;
  int m0 = blockIdx.x * 64 + w * 16;
  int rowA = m0 + m;
  bool rowOK = rowA < N;
  f32x4 acc[4] = {{0.f,0.f,0.f,0.f},{0.f,0.f,0.f,0.f},{0.f,0.f,0.f,0.f},{0.f,0.f,0.f,0.f}};
#pragma unroll
  for (int kc = 0; kc < K / 32; ++kc) {
    short8 a = {0, 0, 0, 0, 0, 0, 0, 0};
    if (rowOK) {
      const float* hp = xv + (size_t)rowA * K + kc * 32 + quad * 8;
      float4 p0 = ((const float4*)hp)[0];
      float4 p1 = ((const float4*)hp)[1];
      a[0] = (short)f2bf(p0.x); a[1] = (short)f2bf(p0.y);
      a[2] = (short)f2bf(p0.z); a[3] = (short)f2bf(p0.w);
      a[4] = (short)f2bf(p1.x); a[5] = (short)f2bf(p1.y);
      a[6] = (short)f2bf(p1.z); a[7] = (short)f2bf(p1.w);
    }
#pragma unroll
    for (int t = 0; t < 4; ++t) {
      short8 b = *(const short8*)(Wt + (size_t)(t * 16 + m) * K + kc * 32 + quad * 8);
      acc[t] = __builtin_amdgcn_mfma_f32_16x16x32_bf16(a, b, acc[t], 0, 0, 0);
    }
  }
  unsigned short* tw = tile[w];
#pragma unroll
  for (int r = 0; r < 4; ++r) {
    int row = quad * 4 + r;
    int gr = m0 + row;
    float dv = dinv[gr < N ? gr : 0];
#pragma unroll
    for (int t = 0; t < 4; ++t)
      tw[row * 68 + t * 16 + m] = f2bf(acc[t][r] * dv);
  }
#pragma unroll
  for (int p = 0; p < 4; ++p) {
    int row = p * 4 + (lane >> 4);
    int ch = lane & 15;  // 4-feature chunk
    int gr = m0 + row;
    if (gr < N) {
      uint2 v = *(const uint2*)(tw + row * 68 + ch * 4);
      float f0 = bf2f((unsigned short)(v.x & 0xFFFFu));
      float f1 = bf2f((unsigned short)(v.x >> 16));
      float f2 = bf2f((unsigned short)(v.y & 0xFFFFu));
      float f3 = bf2f((unsigned short)(v.y >> 16));
      int pk = 0;
      pk = __builtin_amdgcn_cvt_pk_fp8_f32(f0, f1, pk, false);
      pk = __builtin_amdgcn_cvt_pk_fp8_f32(f2, f3, pk, true);
      *(unsigned int*)(out + (size_t)gr * 64 + ch * 4) = (unsigned int)pk;
    }
  }
}

// ---------------- gather core: one node per 4-lane quad, 16B/lane, 16 edges in flight ----------
// 256 rows in flight per wave (2x octet layout). Lane owns 16 features end-to-end.

#define GATHER_CORE(A8in)                                                        \
  f32x2 a0={0.f,0.f},a1={0.f,0.f},a2={0.f,0.f},a3={0.f,0.f};                     \
  f32x2 a4={0.f,0.f},a5={0.f,0.f},a6={0.f,0.f},a7={0.f,0.f};                     \
  for (int base = s; base < e; base += 16) {                                     \
    int i0 = base + l4 * 4;                                                      \
    int r0 = (i0     < e) ? __builtin_nontemporal_load(sorted_src + i0)     : 0; \
    int r1 = (i0 + 1 < e) ? __builtin_nontemporal_load(sorted_src + i0 + 1) : 0; \
    int r2 = (i0 + 2 < e) ? __builtin_nontemporal_load(sorted_src + i0 + 2) : 0; \
    int r3 = (i0 + 3 < e) ? __builtin_nontemporal_load(sorted_src + i0 + 3) : 0; \
    int cnt = e - base; if (cnt > 16) cnt = 16;                                  \
    int rj[16];                                                                  \
    _Pragma("unroll")                                                            \
    for (int s4 = 0; s4 < 4; ++s4) {                                             \
      rj[s4 * 4 + 0] = __shfl(r0, qbase + s4);                                   \
      rj[s4 * 4 + 1] = __shfl(r1, qbase + s4);                                   \
      rj[s4 * 4 + 2] = __shfl(r2, qbase + s4);                                   \
      rj[s4 * 4 + 3] = __shfl(r3, qbase + s4);                                   \
    }                                                                            \
    _Pragma("unroll")                                                            \
    for (int t = 0; t < 16; ++t) {                                               \
      if (t < cnt) {                                                             \
        uint4 v = *(const uint4*)(A8in + ((size_t)(unsigned int)rj[t] << 6) + l4 * 16); \
        a0 += __builtin_amdgcn_cvt_pk_f32_fp8((int)v.x, false);                  \
        a1 += __builtin_amdgcn_cvt_pk_f32_fp8((int)v.x, true);                   \
        a2 += __builtin_amdgcn_cvt_pk_f32_fp8((int)v.y, false);                  \
        a3 += __builtin_amdgcn_cvt_pk_f32_fp8((int)v.y, true);                   \
        a4 += __builtin_amdgcn_cvt_pk_f32_fp8((int)v.z, false);                  \
        a5 += __builtin_amdgcn_cvt_pk_f32_fp8((int)v.z, true);                   \
        a6 += __builtin_amdgcn_cvt_pk_f32_fp8((int)v.w, false);                  \
        a7 += __builtin_amdgcn_cvt_pk_f32_fp8((int)v.w, true);                   \
      }                                                                          \
    }                                                                            \
  }

// ---------------- FUSED: gather-aggregate + bias + ReLU + (h @ Wnext)*dinv -> A8out ----------------
// 64 nodes/block (4-lane quads). h staged in LDS [64][72] bf16 (stride 72 shorts
// = 144B, 16B-aligned rows), 32 MFMAs/block, fp8 pack.

__global__ __launch_bounds__(256) void agg_gemm(const unsigned char* __restrict__ A8in,
                                                const int* __restrict__ offsets,
                                                const int* __restrict__ sorted_src,
                                                const float* __restrict__ dinv,
                                                const float* __restrict__ bias,
                                                const unsigned short* __restrict__ Wt,
                                                unsigned char* __restrict__ A8out, int N) {
  __shared__ unsigned short hl[64 * 72];
  int lane = threadIdx.x & 63;
  int cl = threadIdx.x >> 2;             // local node 0..63
  int c = blockIdx.x * 64 + cl;
  int l4 = lane & 3;                     // 16B chunk of the 64B row
  int qbase = lane & 60;
  bool ok = c < N;
  int s = 0, e = 0;
  float dc = 0.f;
  uint4 svr = {0u, 0u, 0u, 0u};
  if (ok) {
    s = offsets[c]; e = offsets[c + 1];
    dc = dinv[c];
    svr = *(const uint4*)(A8in + ((size_t)c << 6) + l4 * 16);
  }
  GATHER_CORE(A8in)
  // h = relu(agg*dc + b) -> bf16 LDS row (zeros for invalid rows)
  {
    short8 w0 = {0,0,0,0,0,0,0,0}, w1 = {0,0,0,0,0,0,0,0};
    if (ok) {
      a0 += __builtin_amdgcn_cvt_pk_f32_fp8((int)svr.x, false);
      a1 += __builtin_amdgcn_cvt_pk_f32_fp8((int)svr.x, true);
      a2 += __builtin_amdgcn_cvt_pk_f32_fp8((int)svr.y, false);
      a3 += __builtin_amdgcn_cvt_pk_f32_fp8((int)svr.y, true);
      a4 += __builtin_amdgcn_cvt_pk_f32_fp8((int)svr.z, false);
      a5 += __builtin_amdgcn_cvt_pk_f32_fp8((int)svr.z, true);
      a6 += __builtin_amdgcn_cvt_pk_f32_fp8((int)svr.w, false);
      a7 += __builtin_amdgcn_cvt_pk_f32_fp8((int)svr.w, true);
      float accf[16] = {a0[0],a0[1],a1[0],a1[1],a2[0],a2[1],a3[0],a3[1],
                        a4[0],a4[1],a5[0],a5[1],a6[0],a6[1],a7[0],a7[1]};
      const float* bp = bias + l4 * 16;
#pragma unroll
      for (int q = 0; q < 8; ++q) {
        float v = fmaf(accf[q], dc, bp[q]);
        w0[q] = (short)f2bf(v > 0.f ? v : 0.f);
      }
#pragma unroll
      for (int q = 0; q < 8; ++q) {
        float v = fmaf(accf[8 + q], dc, bp[8 + q]);
        w1[q] = (short)f2bf(v > 0.f ? v : 0.f);
      }
    }
    short8* dst = (short8*)(hl + cl * 72 + l4 * 16);
    dst[0] = w0; dst[1] = w1;
  }
  __syncthreads();
  // MFMA: wave wv handles rows wv*16..+15, all 64 cols, K=64
  int wv = threadIdx.x >> 6;
  int m = lane & 15, quad = lane >> 4;
  int rbase = wv * 16;
  f32x4 acc2[4] = {{0.f,0.f,0.f,0.f},{0.f,0.f,0.f,0.f},{0.f,0.f,0.f,0.f},{0.f,0.f,0.f,0.f}};
#pragma unroll
  for (int kc = 0; kc < 2; ++kc) {
    short8 a = *(const short8*)(hl + (rbase + m) * 72 + kc * 32 + quad * 8);
#pragma unroll
    for (int t = 0; t < 4; ++t) {
      short8 b = *(const short8*)(Wt + (size_t)(t * 16 + m) * 64 + kc * 32 + quad * 8);
      acc2[t] = __builtin_amdgcn_mfma_f32_16x16x32_bf16(a, b, acc2[t], 0, 0, 0);
    }
  }
  __syncthreads();   // all reads of hl done; reuse as output tile
#pragma unroll
  for (int r = 0; r < 4; ++r) {
    int row = rbase + quad * 4 + r;
    int gr = blockIdx.x * 64 + row;
    float dv = dinv[gr < N ? gr : 0];
#pragma unroll
    for (int t = 0; t < 4; ++t)
      hl[row * 72 + t * 16 + m] = f2bf(acc2[t][r] * dv);
  }
  __syncthreads();
  // fp8 pack: 64 rows x 16 chunks = 1024 items over 256 threads, coalesced
#pragma unroll
  for (int u = 0; u < 4; ++u) {
    int id = u * 256 + threadIdx.x;
    int row = id >> 4, ch = id & 15;
    int gr = blockIdx.x * 64 + row;
    if (gr < N) {
      uint2 v = *(const uint2*)(hl + row * 72 + ch * 4);
      float f0 = bf2f((unsigned short)(v.x & 0xFFFFu));
      float f1 = bf2f((unsigned short)(v.x >> 16));
      float f2 = bf2f((unsigned short)(v.y & 0xFFFFu));
      float f3 = bf2f((unsigned short)(v.y >> 16));
      int pk = 0;
      pk = __builtin_amdgcn_cvt_pk_fp8_f32(f0, f1, pk, false);
      pk = __builtin_amdgcn_cvt_pk_fp8_f32(f2, f3, pk, true);
      *(unsigned int*)(A8out + (size_t)gr * 64 + ch * 4) = (unsigned int)pk;
    }
  }
}

// ---------------- FUSED: gather-aggregate (layer 3) + MLP head + sigmoid + BCE ----------------

__global__ __launch_bounds__(256) void agg_head(const unsigned char* __restrict__ A8in,
                                                const int* __restrict__ offsets,
                                                const int* __restrict__ sorted_src,
                                                const float* __restrict__ dinv,
                                                const float* __restrict__ bias,
                                                const float* __restrict__ lW1,
                                                const float* __restrict__ lb1,
                                                const float* __restrict__ lW2,
                                                const float* __restrict__ lb2,
                                                const int* __restrict__ labels,
                                                const float* __restrict__ pmsum,
                                                float* __restrict__ p,
                                                float* __restrict__ loss, int N) {
  int lane = threadIdx.x & 63;
  int cl = threadIdx.x >> 2;
  int c = blockIdx.x * 64 + cl;
  int l4 = lane & 3;
  int qbase = lane & 60;
  bool ok = c < N;
  int s = 0, e = 0;
  float dc = 0.f;
  uint4 svr = {0u, 0u, 0u, 0u};
  if (ok) {
    s = offsets[c]; e = offsets[c + 1];
    dc = dinv[c];
    svr = *(const uint4*)(A8in + ((size_t)c << 6) + l4 * 16);
  }
  GATHER_CORE(A8in)
  float contrib = 0.f;
  {
    a0 += __builtin_amdgcn_cvt_pk_f32_fp8((int)svr.x, false);
    a1 += __builtin_amdgcn_cvt_pk_f32_fp8((int)svr.x, true);
    a2 += __builtin_amdgcn_cvt_pk_f32_fp8((int)svr.y, false);
    a3 += __builtin_amdgcn_cvt_pk_f32_fp8((int)svr.y, true);
    a4 += __builtin_amdgcn_cvt_pk_f32_fp8((int)svr.z, false);
    a5 += __builtin_amdgcn_cvt_pk_f32_fp8((int)svr.z, true);
    a6 += __builtin_amdgcn_cvt_pk_f32_fp8((int)svr.w, false);
    a7 += __builtin_amdgcn_cvt_pk_f32_fp8((int)svr.w, true);
    float accf[16] = {a0[0],a0[1],a1[0],a1[1],a2[0],a2[1],a3[0],a3[1],
                      a4[0],a4[1],a5[0],a5[1],a6[0],a6[1],a7[0],a7[1]};
    const float* bp = bias + l4 * 16;
    float hq[16];
#pragma unroll
    for (int q = 0; q < 16; ++q) {
      float v = fmaf(accf[q], dc, bp[q]);
      hq[q] = v > 0.f ? v : 0.f;
    }
    // per-lane partial contraction over this lane's 16 feats
    float acc8[8] = {0.f,0.f,0.f,0.f,0.f,0.f,0.f,0.f};
#pragma unroll
    for (int q = 0; q < 16; ++q) {
      int k = l4 * 16 + q;
#pragma unroll
      for (int j = 0; j < 8; ++j) acc8[j] = fmaf(hq[q], lW1[k * 8 + j], acc8[j]);
    }
    // quad reduce (lanes l^1, l^2 are in the same quad)
#pragma unroll
    for (int j = 0; j < 8; ++j) {
      acc8[j] += __shfl_xor(acc8[j], 1);
      acc8[j] += __shfl_xor(acc8[j], 2);
    }
    if (ok && l4 == 0) {
      float sv = lb2[0];
#pragma unroll
      for (int j = 0; j < 8; ++j) {
        float a = acc8[j] + lb1[j];
        a = a > 0.f ? a : 0.f;
        sv = fmaf(a, lW2[j], sv);
      }
      float pv = 1.0f / (1.0f + expf(-sv));
      p[c] = pv;
      float pm = *pmsum / (float)N;
      float y = (float)labels[c];
      float w = y * (1.f - pm) + (1.f - y) * pm;
      float pc = fminf(fmaxf(pv, 1e-7f), 1.f - 1e-7f);
      float bce = -(y * logf(pc) + (1.f - y) * logf(1.f - pc));
      contrib = w * bce / (float)N;
    }
  }
#pragma unroll
  for (int o = 32; o > 0; o >>= 1) contrib += __shfl_down(contrib, o);
  __shared__ float sh[4];
  int wv = threadIdx.x >> 6;
  if (lane == 0) sh[wv] = contrib;
  __syncthreads();
  if (threadIdx.x == 0) atomicAdd(loss, sh[0] + sh[1] + sh[2] + sh[3]);
}

// ---------------- launch ----------------

extern "C" void kernel_launch(void* const* d_in, const int* in_sizes, int n_in,
                              void* d_out, int out_size, void* d_ws, size_t ws_size,
                              hipStream_t stream) {
  const float* x      = (const float*)d_in[0];
  const int*   ei     = (const int*)d_in[1];
  const int*   labels = (const int*)d_in[2];
  const float* W1 = (const float*)d_in[3];
  const float* b1 = (const float*)d_in[4];
  const float* W2 = (const float*)d_in[5];
  const float* b2 = (const float*)d_in[6];
  const float* W3 = (const float*)d_in[7];
  const float* b3 = (const float*)d_in[8];
  const float* lW1 = (const float*)d_in[9];
  const float* lb1 = (const float*)d_in[10];
  const float* lW2 = (const float*)d_in[11];
  const float* lb2 = (const float*)d_in[12];

  int N = in_sizes[2];            // labels: [N,1]
  int E = in_sizes[1] / 2;        // edge_index: [2,E]
  const int* rows = ei;           // sources
  const int* cols = ei + E;       // targets (aggregation)

  int Npad = (N + 63) & ~63;
  int NBUCK = (N + 255) >> 8;               // 256-node buckets
  int totalH = NBUCK * NBLK;                // histogram entries
  int nb2 = (totalH + 255) / 256;

  // workspace layout
  char* ws = (char*)d_ws;
  unsigned char*  A8a = (unsigned char*)ws;                         // Npad*64 fp8
  unsigned char*  A8b = (unsigned char*)(ws + (size_t)Npad * 64);   // Npad*64 fp8
  unsigned short* Wt1 = (unsigned short*)(ws + (size_t)Npad * 192); // 64*128
  unsigned short* Wt2 = Wt1 + 64 * 128;                 // 64*64
  unsigned short* Wt3 = Wt2 + 64 * 64;                  // 64*64
  float* dinv     = (float*)(Wt3 + 64 * 64);            // N
  int*   offsets  = (int*)(dinv + N);                   // N+1
  int*   histG    = offsets + N + 1;                    // NBLK*NBUCK
  int*   scanned  = histG + totalH;                     // NBLK*NBUCK
  unsigned int* packed = (unsigned int*)(scanned + totalH);  // E
  int*   sorted   = (int*)(packed + E);                 // E
  int*   partials = sorted + E;                         // nb2
  float* pmsum    = (float*)(partials + nb2);           // 1
  float* labelsum = pmsum + 1;                          // NBLK

  float* loss = (float*)d_out;
  float* p    = (float*)d_out + 1;

  int gemmBlocks = Npad / 64;
  int aggBlocks  = (N + 63) / 64;

  // ---- atomic-free CSR build (+ Wt transpose & label-sum folded into hist) ----
  hist_kernel<<<NBLK, 256, 0, stream>>>(cols, histG, labels, labelsum,
                                        W1, W2, W3, Wt1, Wt2, Wt3, E, N, NBUCK);
  scan_partials_t<<<nb2, 256, 0, stream>>>(histG, partials, totalH, NBUCK);
  scan_block<<<1, 256, 0, stream>>>(partials, nb2, loss, labelsum, pmsum);
  scan_final_t<<<nb2, 256, 0, stream>>>(histG, partials, scanned, totalH, NBUCK);
  scatter_kernel<<<NBLK, 256, 0, stream>>>(rows, cols, scanned, packed, E, NBUCK);
  csr_finalize<<<NBUCK, 1024, 0, stream>>>(packed, scanned, sorted, offsets, dinv, N, E, NBUCK);

  // ---- layer 1 GEMM (K=128, fp32 x converted in-flight) ----
  mfma_gemm1<<<gemmBlocks, 256, 0, stream>>>(x, Wt1, dinv, A8a, N);

  // ---- fused layers: agg1+gemm2, agg2+gemm3, agg3+head ----
  agg_gemm<<<aggBlocks, 256, 0, stream>>>(A8a, offsets, sorted, dinv, b1, Wt2, A8b, N);
  agg_gemm<<<aggBlocks, 256, 0, stream>>>(A8b, offsets, sorted, dinv, b2, Wt3, A8a, N);
  agg_head<<<aggBlocks, 256, 0, stream>>>(A8a, offsets, sorted, dinv, b3,
                                          lW1, lb1, lW2, lb2, labels, pmsum, p, loss, N);
}

// Round 7
// 278.548 us; speedup vs baseline: 4.5922x; 1.0985x over previous
//
#include <hip/hip_runtime.h>
#include <cstdint>
#include <cstddef>

typedef __attribute__((ext_vector_type(8))) short short8;
typedef __attribute__((ext_vector_type(4))) float f32x4;
typedef __attribute__((ext_vector_type(2))) float f32x2;

#define NBLK 512        // edge-chunk blocks for hist/scatter (pow2)
#define NBLK_SHIFT 9

__device__ inline unsigned short f2bf(float f) {
  union { float f; unsigned int u; } x; x.f = f;
  unsigned int r = x.u + 0x7FFFu + ((x.u >> 16) & 1u);  // round-to-nearest-even
  return (unsigned short)(r >> 16);
}
__device__ inline float bf2f(unsigned short s) {
  union { unsigned int u; float f; } x; x.u = ((unsigned int)s) << 16;
  return x.f;
}

// ---------------- P1: per-block bucket histogram (LDS atomics only) ----------------
// blocks 0..2 transpose W1..W3; block 3 zeroes the gather zero-rows of A8a/A8b.

__global__ __launch_bounds__(256) void hist_kernel(const int* __restrict__ cols,
                                                   int* __restrict__ histG,
                                                   const int* __restrict__ labels,
                                                   float* __restrict__ labelsum,
                                                   const float* __restrict__ W1,
                                                   const float* __restrict__ W2,
                                                   const float* __restrict__ W3,
                                                   unsigned short* __restrict__ Wt1,
                                                   unsigned short* __restrict__ Wt2,
                                                   unsigned short* __restrict__ Wt3,
                                                   unsigned char* __restrict__ zrow_a,
                                                   unsigned char* __restrict__ zrow_b,
                                                   int E, int N, int NBUCK) {
  __shared__ int h[512];
  if (blockIdx.x < 3) {
    const float* W; unsigned short* Wt; int K;
    if (blockIdx.x == 0)      { W = W1; Wt = Wt1; K = 128; }
    else if (blockIdx.x == 1) { W = W2; Wt = Wt2; K = 64; }
    else                      { W = W3; Wt = Wt3; K = 64; }
    int total = K * 64;
    for (int i = threadIdx.x; i < total; i += 256) {
      int n = i / K, k = i - n * K;  // Wt[n][k] = W[k][n]
      Wt[i] = f2bf(W[k * 64 + n]);
    }
  } else if (blockIdx.x == 3 && threadIdx.x < 32) {
    if (threadIdx.x < 16) ((unsigned int*)zrow_a)[threadIdx.x] = 0u;
    else                  ((unsigned int*)zrow_b)[threadIdx.x - 16] = 0u;
  }
  {
    int chunkL = (N + NBLK - 1) / NBLK;
    int ls = blockIdx.x * chunkL;
    int le = min(N, ls + chunkL);
    float v = 0.f;
    for (int i = ls + threadIdx.x; i < le; i += 256) v += (float)labels[i];
#pragma unroll
    for (int o = 32; o > 0; o >>= 1) v += __shfl_down(v, o);
    __shared__ float sl[4];
    if ((threadIdx.x & 63) == 0) sl[threadIdx.x >> 6] = v;
    __syncthreads();
    if (threadIdx.x == 0) labelsum[blockIdx.x] = sl[0] + sl[1] + sl[2] + sl[3];
  }
  for (int i = threadIdx.x; i < NBUCK; i += 256) h[i] = 0;
  __syncthreads();
  int chunk = (E + NBLK - 1) / NBLK;
  int s = blockIdx.x * chunk;
  int e = min(E, s + chunk);
  for (int i = s + threadIdx.x; i < e; i += 256) atomicAdd(&h[cols[i] >> 8], 1);
  __syncthreads();
  for (int i = threadIdx.x; i < NBUCK; i += 256)
    histG[blockIdx.x * NBUCK + i] = h[i];
}

// ---------------- P2: scan of NBUCK*NBLK counts, bucket-major logical order ----------------

__global__ __launch_bounds__(256) void scan_partials_t(const int* __restrict__ histG,
                                                       int* __restrict__ partials,
                                                       int total, int NBUCK) {
  int i = blockIdx.x * 256 + threadIdx.x;
  int v = 0;
  if (i < total) {
    int bucket = i >> NBLK_SHIFT, blk = i & (NBLK - 1);
    v = histG[blk * NBUCK + bucket];
  }
#pragma unroll
  for (int o = 32; o > 0; o >>= 1) v += __shfl_down(v, o);
  __shared__ int s[4];
  if ((threadIdx.x & 63) == 0) s[threadIdx.x >> 6] = v;
  __syncthreads();
  if (threadIdx.x == 0) partials[blockIdx.x] = s[0] + s[1] + s[2] + s[3];
}

__global__ __launch_bounds__(256) void scan_block(int* __restrict__ partials, int nb,
                                                  float* __restrict__ loss,
                                                  const float* __restrict__ labelsum,
                                                  float* __restrict__ pmsum) {
  __shared__ int tmp[256];
  __shared__ int carry;
  int tid = threadIdx.x;
  {
    float v = 0.f;
    for (int i = tid; i < NBLK; i += 256) v += labelsum[i];
#pragma unroll
    for (int o = 32; o > 0; o >>= 1) v += __shfl_down(v, o);
    __shared__ float sl[4];
    if ((tid & 63) == 0) sl[tid >> 6] = v;
    __syncthreads();
    if (tid == 0) *pmsum = sl[0] + sl[1] + sl[2] + sl[3];
  }
  if (tid == 0) { carry = 0; *loss = 0.f; }
  __syncthreads();
  for (int base = 0; base < nb; base += 256) {
    int i = base + tid;
    int v = (i < nb) ? partials[i] : 0;
    tmp[tid] = v;
    __syncthreads();
    int incl = v;
    for (int o = 1; o < 256; o <<= 1) {
      int t = (tid >= o) ? tmp[tid - o] : 0;
      __syncthreads();
      incl += t;
      tmp[tid] = incl;
      __syncthreads();
    }
    int total = tmp[255];
    int c = carry;
    if (i < nb) partials[i] = c + incl - v;  // exclusive
    __syncthreads();
    if (tid == 0) carry = c + total;
    __syncthreads();
  }
}

__global__ __launch_bounds__(256) void scan_final_t(const int* __restrict__ histG,
                                                    const int* __restrict__ partials,
                                                    int* __restrict__ scannedG,
                                                    int total, int NBUCK) {
  __shared__ int tmp[256];
  int tid = threadIdx.x;
  int i = blockIdx.x * 256 + tid;
  int bucket = i >> NBLK_SHIFT, blk = i & (NBLK - 1);
  int v = (i < total) ? histG[blk * NBUCK + bucket] : 0;
  tmp[tid] = v;
  __syncthreads();
  int incl = v;
  for (int o = 1; o < 256; o <<= 1) {
    int t = (tid >= o) ? tmp[tid - o] : 0;
    __syncthreads();
    incl += t;
    tmp[tid] = incl;
    __syncthreads();
  }
  if (i < total) scannedG[blk * NBUCK + bucket] = partials[blockIdx.x] + incl - v;
}

// ---------------- P3: bucket-partition scatter (LDS cursors, no global atomics) ----------------

__global__ __launch_bounds__(256) void scatter_kernel(const int* __restrict__ rows,
                                                      const int* __restrict__ cols,
                                                      const int* __restrict__ scannedG,
                                                      unsigned int* __restrict__ packed,
                                                      int E, int NBUCK) {
  __shared__ int cur[512];
  for (int i = threadIdx.x; i < NBUCK; i += 256)
    cur[i] = scannedG[blockIdx.x * NBUCK + i];
  __syncthreads();
  int chunk = (E + NBLK - 1) / NBLK;
  int s = blockIdx.x * chunk;
  int e = min(E, s + chunk);
  for (int i = s + threadIdx.x; i < e; i += 256) {
    int c = cols[i];
    int r = rows[i];
    int pos = atomicAdd(&cur[c >> 8], 1);
    packed[pos] = ((unsigned int)(c & 255) << 24) | (unsigned int)r;
  }
}

// ---------------- P4: per-bucket CSR finalize (1024 threads/block) ----------------

__global__ __launch_bounds__(1024) void csr_finalize(const unsigned int* __restrict__ packed,
                                                     const int* __restrict__ scannedG,
                                                     int* __restrict__ sorted_src,
                                                     int* __restrict__ offsets,
                                                     float* __restrict__ dinv,
                                                     int N, int E, int NBUCK) {
  __shared__ int h[256];
  __shared__ int tmp[256];
  __shared__ int cur[256];
  int b = blockIdx.x;
  int tid = threadIdx.x;
  int base = scannedG[b];
  int end = (b + 1 < NBUCK) ? scannedG[b + 1] : E;
  if (tid < 256) h[tid] = 0;
  __syncthreads();
  for (int i = base + tid; i < end; i += 1024)
    atomicAdd(&h[packed[i] >> 24], 1);
  __syncthreads();
  if (tid < 256) {
    int v = h[tid];
    tmp[tid] = v;
  }
  __syncthreads();
  if (tid < 256) {
    int v = h[tid];
    int incl = v;
    for (int o = 1; o < 256; o <<= 1) {
      int t = (tid >= o) ? tmp[tid - o] : 0;
      __syncthreads();
      incl += t;
      tmp[tid] = incl;
      __syncthreads();
    }
    int excl = incl - v;
    int node = b * 256 + tid;
    if (node < N) {
      offsets[node] = base + excl;
      dinv[node] = rsqrtf((float)(v + 1));  // +1 self loop
    }
    cur[tid] = base + excl;
    if (b == NBUCK - 1 && tid == 0) offsets[N] = E;
  } else {
    for (int o = 1; o < 256; o <<= 1) { __syncthreads(); __syncthreads(); }
  }
  __syncthreads();
  for (int i = base + tid; i < end; i += 1024) {
    unsigned int p = packed[i];
    int pos = atomicAdd(&cur[p >> 24], 1);
    sorted_src[pos] = (int)(p & 0xFFFFFFu);
  }
}

// ---------------- MFMA GEMM (layer 1 only): A_fp8[N,64] = (x[N,128] @ W1) * dinv[n] ----------------

__global__ __launch_bounds__(256) void mfma_gemm1(const float* __restrict__ xv,
                                                  const unsigned short* __restrict__ Wt,
                                                  const float* __restrict__ dinv,
                                                  unsigned char* __restrict__ out, int N) {
  const int K = 128;
  __shared__ unsigned short tile[4][16 * 68];
  int w = threadIdx.x >> 6, lane = threadIdx.x & 63;
  int m = lane & 15, quad = lane >> 4;
  int m0 = blockIdx.x * 64 + w * 16;
  int rowA = m0 + m;
  bool rowOK = rowA < N;
  f32x4 acc[4] = {{0.f,0.f,0.f,0.f},{0.f,0.f,0.f,0.f},{0.f,0.f,0.f,0.f},{0.f,0.f,0.f,0.f}};
#pragma unroll
  for (int kc = 0; kc < K / 32; ++kc) {
    short8 a = {0, 0, 0, 0, 0, 0, 0, 0};
    if (rowOK) {
      const float* hp = xv + (size_t)rowA * K + kc * 32 + quad * 8;
      float4 p0 = ((const float4*)hp)[0];
      float4 p1 = ((const float4*)hp)[1];
      a[0] = (short)f2bf(p0.x); a[1] = (short)f2bf(p0.y);
      a[2] = (short)f2bf(p0.z); a[3] = (short)f2bf(p0.w);
      a[4] = (short)f2bf(p1.x); a[5] = (short)f2bf(p1.y);
      a[6] = (short)f2bf(p1.z); a[7] = (short)f2bf(p1.w);
    }
#pragma unroll
    for (int t = 0; t < 4; ++t) {
      short8 b = *(const short8*)(Wt + (size_t)(t * 16 + m) * K + kc * 32 + quad * 8);
      acc[t] = __builtin_amdgcn_mfma_f32_16x16x32_bf16(a, b, acc[t], 0, 0, 0);
    }
  }
  unsigned short* tw = tile[w];
#pragma unroll
  for (int r = 0; r < 4; ++r) {
    int row = quad * 4 + r;
    int gr = m0 + row;
    float dv = dinv[gr < N ? gr : 0];
#pragma unroll
    for (int t = 0; t < 4; ++t)
      tw[row * 68 + t * 16 + m] = f2bf(acc[t][r] * dv);
  }
#pragma unroll
  for (int p = 0; p < 4; ++p) {
    int row = p * 4 + (lane >> 4);
    int ch = lane & 15;  // 4-feature chunk
    int gr = m0 + row;
    if (gr < N) {
      uint2 v = *(const uint2*)(tw + row * 68 + ch * 4);
      float f0 = bf2f((unsigned short)(v.x & 0xFFFFu));
      float f1 = bf2f((unsigned short)(v.x >> 16));
      float f2 = bf2f((unsigned short)(v.y & 0xFFFFu));
      float f3 = bf2f((unsigned short)(v.y >> 16));
      int pk = 0;
      pk = __builtin_amdgcn_cvt_pk_fp8_f32(f0, f1, pk, false);
      pk = __builtin_amdgcn_cvt_pk_fp8_f32(f2, f3, pk, true);
      *(unsigned int*)(out + (size_t)gr * 64 + ch * 4) = (unsigned int)pk;
    }
  }
}

// ---------------- gather core: one node per 4-lane quad, 16B/lane, BRANCHLESS ----------------
// Invalid edge slots are clamped to the zero-row (index ZR); all 16 uint4 loads
// issue unconditionally into a compile-time-indexed array -> full batch in flight.

#define GATHER_CORE(A8in, ZR)                                                    \
  f32x2 a0={0.f,0.f},a1={0.f,0.f},a2={0.f,0.f},a3={0.f,0.f};                     \
  f32x2 a4={0.f,0.f},a5={0.f,0.f},a6={0.f,0.f},a7={0.f,0.f};                     \
  for (int base = s; base < e; base += 16) {                                     \
    int i0 = base + l4 * 4;                                                      \
    int r0 = (i0     < e) ? __builtin_nontemporal_load(sorted_src + i0)     : ZR;\
    int r1 = (i0 + 1 < e) ? __builtin_nontemporal_load(sorted_src + i0 + 1) : ZR;\
    int r2 = (i0 + 2 < e) ? __builtin_nontemporal_load(sorted_src + i0 + 2) : ZR;\
    int r3 = (i0 + 3 < e) ? __builtin_nontemporal_load(sorted_src + i0 + 3) : ZR;\
    int rj[16];                                                                  \
    _Pragma("unroll")                                                            \
    for (int s4 = 0; s4 < 4; ++s4) {                                             \
      rj[s4 * 4 + 0] = __shfl(r0, qbase + s4);                                   \
      rj[s4 * 4 + 1] = __shfl(r1, qbase + s4);                                   \
      rj[s4 * 4 + 2] = __shfl(r2, qbase + s4);                                   \
      rj[s4 * 4 + 3] = __shfl(r3, qbase + s4);                                   \
    }                                                                            \
    uint4 v[16];                                                                 \
    _Pragma("unroll")                                                            \
    for (int t = 0; t < 16; ++t)                                                 \
      v[t] = *(const uint4*)(A8in + ((size_t)(unsigned int)rj[t] << 6) + l4 * 16);\
    _Pragma("unroll")                                                            \
    for (int t = 0; t < 16; ++t) {                                               \
      a0 += __builtin_amdgcn_cvt_pk_f32_fp8((int)v[t].x, false);                 \
      a1 += __builtin_amdgcn_cvt_pk_f32_fp8((int)v[t].x, true);                  \
      a2 += __builtin_amdgcn_cvt_pk_f32_fp8((int)v[t].y, false);                 \
      a3 += __builtin_amdgcn_cvt_pk_f32_fp8((int)v[t].y, true);                  \
      a4 += __builtin_amdgcn_cvt_pk_f32_fp8((int)v[t].z, false);                 \
      a5 += __builtin_amdgcn_cvt_pk_f32_fp8((int)v[t].z, true);                  \
      a6 += __builtin_amdgcn_cvt_pk_f32_fp8((int)v[t].w, false);                 \
      a7 += __builtin_amdgcn_cvt_pk_f32_fp8((int)v[t].w, true);                  \
    }                                                                            \
  }

// ---------------- FUSED: gather-aggregate + bias + ReLU + (h @ Wnext)*dinv -> A8out ----------------
// 64 nodes/block (4-lane quads). h staged in LDS [64][72] bf16, 32 MFMAs/block.
// __launch_bounds__(256,4): VGPR cap 128 so the 16-load gather batch stays in regs.

__global__ __launch_bounds__(256, 4) void agg_gemm(const unsigned char* __restrict__ A8in,
                                                   const int* __restrict__ offsets,
                                                   const int* __restrict__ sorted_src,
                                                   const float* __restrict__ dinv,
                                                   const float* __restrict__ bias,
                                                   const unsigned short* __restrict__ Wt,
                                                   unsigned char* __restrict__ A8out,
                                                   int N, int ZR) {
  __shared__ unsigned short hl[64 * 72];
  int lane = threadIdx.x & 63;
  int cl = threadIdx.x >> 2;             // local node 0..63
  int c = blockIdx.x * 64 + cl;
  int l4 = lane & 3;                     // 16B chunk of the 64B row
  int qbase = lane & 60;
  bool ok = c < N;
  int s = 0, e = 0;
  float dc = 0.f;
  uint4 svr = {0u, 0u, 0u, 0u};
  if (ok) {
    s = offsets[c]; e = offsets[c + 1];
    dc = dinv[c];
    svr = *(const uint4*)(A8in + ((size_t)c << 6) + l4 * 16);
  }
  GATHER_CORE(A8in, ZR)
  // h = relu(agg*dc + b) -> bf16 LDS row (zeros for invalid rows)
  {
    short8 w0 = {0,0,0,0,0,0,0,0}, w1 = {0,0,0,0,0,0,0,0};
    if (ok) {
      a0 += __builtin_amdgcn_cvt_pk_f32_fp8((int)svr.x, false);
      a1 += __builtin_amdgcn_cvt_pk_f32_fp8((int)svr.x, true);
      a2 += __builtin_amdgcn_cvt_pk_f32_fp8((int)svr.y, false);
      a3 += __builtin_amdgcn_cvt_pk_f32_fp8((int)svr.y, true);
      a4 += __builtin_amdgcn_cvt_pk_f32_fp8((int)svr.z, false);
      a5 += __builtin_amdgcn_cvt_pk_f32_fp8((int)svr.z, true);
      a6 += __builtin_amdgcn_cvt_pk_f32_fp8((int)svr.w, false);
      a7 += __builtin_amdgcn_cvt_pk_f32_fp8((int)svr.w, true);
      float accf[16] = {a0[0],a0[1],a1[0],a1[1],a2[0],a2[1],a3[0],a3[1],
                        a4[0],a4[1],a5[0],a5[1],a6[0],a6[1],a7[0],a7[1]};
      const float* bp = bias + l4 * 16;
#pragma unroll
      for (int q = 0; q < 8; ++q) {
        float v = fmaf(accf[q], dc, bp[q]);
        w0[q] = (short)f2bf(v > 0.f ? v : 0.f);
      }
#pragma unroll
      for (int q = 0; q < 8; ++q) {
        float v = fmaf(accf[8 + q], dc, bp[8 + q]);
        w1[q] = (short)f2bf(v > 0.f ? v : 0.f);
      }
    }
    short8* dst = (short8*)(hl + cl * 72 + l4 * 16);
    dst[0] = w0; dst[1] = w1;
  }
  __syncthreads();
  // MFMA: wave wv handles rows wv*16..+15, all 64 cols, K=64
  int wv = threadIdx.x >> 6;
  int m = lane & 15, quad = lane >> 4;
  int rbase = wv * 16;
  f32x4 acc2[4] = {{0.f,0.f,0.f,0.f},{0.f,0.f,0.f,0.f},{0.f,0.f,0.f,0.f},{0.f,0.f,0.f,0.f}};
#pragma unroll
  for (int kc = 0; kc < 2; ++kc) {
    short8 a = *(const short8*)(hl + (rbase + m) * 72 + kc * 32 + quad * 8);
#pragma unroll
    for (int t = 0; t < 4; ++t) {
      short8 b = *(const short8*)(Wt + (size_t)(t * 16 + m) * 64 + kc * 32 + quad * 8);
      acc2[t] = __builtin_amdgcn_mfma_f32_16x16x32_bf16(a, b, acc2[t], 0, 0, 0);
    }
  }
  __syncthreads();   // all reads of hl done; reuse as output tile
#pragma unroll
  for (int r = 0; r < 4; ++r) {
    int row = rbase + quad * 4 + r;
    int gr = blockIdx.x * 64 + row;
    float dv = dinv[gr < N ? gr : 0];
#pragma unroll
    for (int t = 0; t < 4; ++t)
      hl[row * 72 + t * 16 + m] = f2bf(acc2[t][r] * dv);
  }
  __syncthreads();
  // fp8 pack: 64 rows x 16 chunks = 1024 items over 256 threads, coalesced
#pragma unroll
  for (int u = 0; u < 4; ++u) {
    int id = u * 256 + threadIdx.x;
    int row = id >> 4, ch = id & 15;
    int gr = blockIdx.x * 64 + row;
    if (gr < N) {
      uint2 v = *(const uint2*)(hl + row * 72 + ch * 4);
      float f0 = bf2f((unsigned short)(v.x & 0xFFFFu));
      float f1 = bf2f((unsigned short)(v.x >> 16));
      float f2 = bf2f((unsigned short)(v.y & 0xFFFFu));
      float f3 = bf2f((unsigned short)(v.y >> 16));
      int pk = 0;
      pk = __builtin_amdgcn_cvt_pk_fp8_f32(f0, f1, pk, false);
      pk = __builtin_amdgcn_cvt_pk_fp8_f32(f2, f3, pk, true);
      *(unsigned int*)(A8out + (size_t)gr * 64 + ch * 4) = (unsigned int)pk;
    }
  }
}

// ---------------- FUSED: gather-aggregate (layer 3) + MLP head + sigmoid + BCE ----------------

__global__ __launch_bounds__(256, 4) void agg_head(const unsigned char* __restrict__ A8in,
                                                   const int* __restrict__ offsets,
                                                   const int* __restrict__ sorted_src,
                                                   const float* __restrict__ dinv,
                                                   const float* __restrict__ bias,
                                                   const float* __restrict__ lW1,
                                                   const float* __restrict__ lb1,
                                                   const float* __restrict__ lW2,
                                                   const float* __restrict__ lb2,
                                                   const int* __restrict__ labels,
                                                   const float* __restrict__ pmsum,
                                                   float* __restrict__ p,
                                                   float* __restrict__ loss,
                                                   int N, int ZR) {
  int lane = threadIdx.x & 63;
  int cl = threadIdx.x >> 2;
  int c = blockIdx.x * 64 + cl;
  int l4 = lane & 3;
  int qbase = lane & 60;
  bool ok = c < N;
  int s = 0, e = 0;
  float dc = 0.f;
  uint4 svr = {0u, 0u, 0u, 0u};
  if (ok) {
    s = offsets[c]; e = offsets[c + 1];
    dc = dinv[c];
    svr = *(const uint4*)(A8in + ((size_t)c << 6) + l4 * 16);
  }
  GATHER_CORE(A8in, ZR)
  float contrib = 0.f;
  {
    a0 += __builtin_amdgcn_cvt_pk_f32_fp8((int)svr.x, false);
    a1 += __builtin_amdgcn_cvt_pk_f32_fp8((int)svr.x, true);
    a2 += __builtin_amdgcn_cvt_pk_f32_fp8((int)svr.y, false);
    a3 += __builtin_amdgcn_cvt_pk_f32_fp8((int)svr.y, true);
    a4 += __builtin_amdgcn_cvt_pk_f32_fp8((int)svr.z, false);
    a5 += __builtin_amdgcn_cvt_pk_f32_fp8((int)svr.z, true);
    a6 += __builtin_amdgcn_cvt_pk_f32_fp8((int)svr.w, false);
    a7 += __builtin_amdgcn_cvt_pk_f32_fp8((int)svr.w, true);
    float accf[16] = {a0[0],a0[1],a1[0],a1[1],a2[0],a2[1],a3[0],a3[1],
                      a4[0],a4[1],a5[0],a5[1],a6[0],a6[1],a7[0],a7[1]};
    const float* bp = bias + l4 * 16;
    float hq[16];
#pragma unroll
    for (int q = 0; q < 16; ++q) {
      float v = fmaf(accf[q], dc, bp[q]);
      hq[q] = v > 0.f ? v : 0.f;
    }
    // per-lane partial contraction over this lane's 16 feats
    float acc8[8] = {0.f,0.f,0.f,0.f,0.f,0.f,0.f,0.f};
#pragma unroll
    for (int q = 0; q < 16; ++q) {
      int k = l4 * 16 + q;
#pragma unroll
      for (int j = 0; j < 8; ++j) acc8[j] = fmaf(hq[q], lW1[k * 8 + j], acc8[j]);
    }
    // quad reduce (lanes l^1, l^2 are in the same quad)
#pragma unroll
    for (int j = 0; j < 8; ++j) {
      acc8[j] += __shfl_xor(acc8[j], 1);
      acc8[j] += __shfl_xor(acc8[j], 2);
    }
    if (ok && l4 == 0) {
      float sv = lb2[0];
#pragma unroll
      for (int j = 0; j < 8; ++j) {
        float a = acc8[j] + lb1[j];
        a = a > 0.f ? a : 0.f;
        sv = fmaf(a, lW2[j], sv);
      }
      float pv = 1.0f / (1.0f + expf(-sv));
      p[c] = pv;
      float pm = *pmsum / (float)N;
      float y = (float)labels[c];
      float w = y * (1.f - pm) + (1.f - y) * pm;
      float pc = fminf(fmaxf(pv, 1e-7f), 1.f - 1e-7f);
      float bce = -(y * logf(pc) + (1.f - y) * logf(1.f - pc));
      contrib = w * bce / (float)N;
    }
  }
#pragma unroll
  for (int o = 32; o > 0; o >>= 1) contrib += __shfl_down(contrib, o);
  __shared__ float sh[4];
  int wv = threadIdx.x >> 6;
  if (lane == 0) sh[wv] = contrib;
  __syncthreads();
  if (threadIdx.x == 0) atomicAdd(loss, sh[0] + sh[1] + sh[2] + sh[3]);
}

// ---------------- launch ----------------

extern "C" void kernel_launch(void* const* d_in, const int* in_sizes, int n_in,
                              void* d_out, int out_size, void* d_ws, size_t ws_size,
                              hipStream_t stream) {
  const float* x      = (const float*)d_in[0];
  const int*   ei     = (const int*)d_in[1];
  const int*   labels = (const int*)d_in[2];
  const float* W1 = (const float*)d_in[3];
  const float* b1 = (const float*)d_in[4];
  const float* W2 = (const float*)d_in[5];
  const float* b2 = (const float*)d_in[6];
  const float* W3 = (const float*)d_in[7];
  const float* b3 = (const float*)d_in[8];
  const float* lW1 = (const float*)d_in[9];
  const float* lb1 = (const float*)d_in[10];
  const float* lW2 = (const float*)d_in[11];
  const float* lb2 = (const float*)d_in[12];

  int N = in_sizes[2];            // labels: [N,1]
  int E = in_sizes[1] / 2;        // edge_index: [2,E]
  const int* rows = ei;           // sources
  const int* cols = ei + E;       // targets (aggregation)

  int Npad = (N + 63) & ~63;
  int NBUCK = (N + 255) >> 8;               // 256-node buckets
  int totalH = NBUCK * NBLK;                // histogram entries
  int nb2 = (totalH + 255) / 256;

  // workspace layout: A8 buffers have one extra zero-row at index Npad (gather clamp)
  size_t a8stride = (size_t)Npad * 64 + 256;
  char* ws = (char*)d_ws;
  unsigned char*  A8a = (unsigned char*)ws;
  unsigned char*  A8b = (unsigned char*)(ws + a8stride);
  unsigned short* Wt1 = (unsigned short*)(ws + (size_t)Npad * 192); // 64*128
  unsigned short* Wt2 = Wt1 + 64 * 128;                 // 64*64
  unsigned short* Wt3 = Wt2 + 64 * 64;                  // 64*64
  float* dinv     = (float*)(Wt3 + 64 * 64);            // N
  int*   offsets  = (int*)(dinv + N);                   // N+1
  int*   histG    = offsets + N + 1;                    // NBLK*NBUCK
  int*   scanned  = histG + totalH;                     // NBLK*NBUCK
  unsigned int* packed = (unsigned int*)(scanned + totalH);  // E
  int*   sorted   = (int*)(packed + E);                 // E
  int*   partials = sorted + E;                         // nb2
  float* pmsum    = (float*)(partials + nb2);           // 1
  float* labelsum = pmsum + 1;                          // NBLK

  float* loss = (float*)d_out;
  float* p    = (float*)d_out + 1;

  int gemmBlocks = Npad / 64;
  int aggBlocks  = (N + 63) / 64;
  int ZR = Npad;                   // zero-row index

  // ---- atomic-free CSR build (+ Wt transpose, zero-rows & label-sum folded into hist) ----
  hist_kernel<<<NBLK, 256, 0, stream>>>(cols, histG, labels, labelsum,
                                        W1, W2, W3, Wt1, Wt2, Wt3,
                                        A8a + (size_t)Npad * 64, A8b + (size_t)Npad * 64,
                                        E, N, NBUCK);
  scan_partials_t<<<nb2, 256, 0, stream>>>(histG, partials, totalH, NBUCK);
  scan_block<<<1, 256, 0, stream>>>(partials, nb2, loss, labelsum, pmsum);
  scan_final_t<<<nb2, 256, 0, stream>>>(histG, partials, scanned, totalH, NBUCK);
  scatter_kernel<<<NBLK, 256, 0, stream>>>(rows, cols, scanned, packed, E, NBUCK);
  csr_finalize<<<NBUCK, 1024, 0, stream>>>(packed, scanned, sorted, offsets, dinv, N, E, NBUCK);

  // ---- layer 1 GEMM (K=128, fp32 x converted in-flight) ----
  mfma_gemm1<<<gemmBlocks, 256, 0, stream>>>(x, Wt1, dinv, A8a, N);

  // ---- fused layers: agg1+gemm2, agg2+gemm3, agg3+head ----
  agg_gemm<<<aggBlocks, 256, 0, stream>>>(A8a, offsets, sorted, dinv, b1, Wt2, A8b, N, ZR);
  agg_gemm<<<aggBlocks, 256, 0, stream>>>(A8b, offsets, sorted, dinv, b2, Wt3, A8a, N, ZR);
  agg_head<<<aggBlocks, 256, 0, stream>>>(A8a, offsets, sorted, dinv, b3,
                                          lW1, lb1, lW2, lb2, labels, pmsum, p, loss, N, ZR);
}

// Round 8
// 278.461 us; speedup vs baseline: 4.5936x; 1.0003x over previous
//
#include <hip/hip_runtime.h>
#include <cstdint>
#include <cstddef>

typedef __attribute__((ext_vector_type(8))) short short8;
typedef __attribute__((ext_vector_type(4))) float f32x4;
typedef __attribute__((ext_vector_type(2))) float f32x2;

#define NBLK 512        // edge-chunk blocks for hist/scatter (pow2)
#define NBLK_SHIFT 9

__device__ inline unsigned short f2bf(float f) {
  union { float f; unsigned int u; } x; x.f = f;
  unsigned int r = x.u + 0x7FFFu + ((x.u >> 16) & 1u);  // round-to-nearest-even
  return (unsigned short)(r >> 16);
}
__device__ inline float bf2f(unsigned short s) {
  union { unsigned int u; float f; } x; x.u = ((unsigned int)s) << 16;
  return x.f;
}

// ---------------- P1: per-block bucket histogram (LDS atomics only) ----------------
// blocks 0..2 transpose W1..W3; block 3 zeroes the gather zero-rows of A8a/A8b.

__global__ __launch_bounds__(256) void hist_kernel(const int* __restrict__ cols,
                                                   int* __restrict__ histG,
                                                   const int* __restrict__ labels,
                                                   float* __restrict__ labelsum,
                                                   const float* __restrict__ W1,
                                                   const float* __restrict__ W2,
                                                   const float* __restrict__ W3,
                                                   unsigned short* __restrict__ Wt1,
                                                   unsigned short* __restrict__ Wt2,
                                                   unsigned short* __restrict__ Wt3,
                                                   unsigned char* __restrict__ zrow_a,
                                                   unsigned char* __restrict__ zrow_b,
                                                   int E, int N, int NBUCK) {
  __shared__ int h[512];
  if (blockIdx.x < 3) {
    const float* W; unsigned short* Wt; int K;
    if (blockIdx.x == 0)      { W = W1; Wt = Wt1; K = 128; }
    else if (blockIdx.x == 1) { W = W2; Wt = Wt2; K = 64; }
    else                      { W = W3; Wt = Wt3; K = 64; }
    int total = K * 64;
    for (int i = threadIdx.x; i < total; i += 256) {
      int n = i / K, k = i - n * K;  // Wt[n][k] = W[k][n]
      Wt[i] = f2bf(W[k * 64 + n]);
    }
  } else if (blockIdx.x == 3 && threadIdx.x < 32) {
    if (threadIdx.x < 16) ((unsigned int*)zrow_a)[threadIdx.x] = 0u;
    else                  ((unsigned int*)zrow_b)[threadIdx.x - 16] = 0u;
  }
  {
    int chunkL = (N + NBLK - 1) / NBLK;
    int ls = blockIdx.x * chunkL;
    int le = min(N, ls + chunkL);
    float v = 0.f;
    for (int i = ls + threadIdx.x; i < le; i += 256) v += (float)labels[i];
#pragma unroll
    for (int o = 32; o > 0; o >>= 1) v += __shfl_down(v, o);
    __shared__ float sl[4];
    if ((threadIdx.x & 63) == 0) sl[threadIdx.x >> 6] = v;
    __syncthreads();
    if (threadIdx.x == 0) labelsum[blockIdx.x] = sl[0] + sl[1] + sl[2] + sl[3];
  }
  for (int i = threadIdx.x; i < NBUCK; i += 256) h[i] = 0;
  __syncthreads();
  int chunk = (E + NBLK - 1) / NBLK;
  int s = blockIdx.x * chunk;
  int e = min(E, s + chunk);
  for (int i = s + threadIdx.x; i < e; i += 256) atomicAdd(&h[cols[i] >> 8], 1);
  __syncthreads();
  for (int i = threadIdx.x; i < NBUCK; i += 256)
    histG[blockIdx.x * NBUCK + i] = h[i];
}

// ---------------- P2: scan of NBUCK*NBLK counts, bucket-major logical order ----------------

__global__ __launch_bounds__(256) void scan_partials_t(const int* __restrict__ histG,
                                                       int* __restrict__ partials,
                                                       int total, int NBUCK) {
  int i = blockIdx.x * 256 + threadIdx.x;
  int v = 0;
  if (i < total) {
    int bucket = i >> NBLK_SHIFT, blk = i & (NBLK - 1);
    v = histG[blk * NBUCK + bucket];
  }
#pragma unroll
  for (int o = 32; o > 0; o >>= 1) v += __shfl_down(v, o);
  __shared__ int s[4];
  if ((threadIdx.x & 63) == 0) s[threadIdx.x >> 6] = v;
  __syncthreads();
  if (threadIdx.x == 0) partials[blockIdx.x] = s[0] + s[1] + s[2] + s[3];
}

__global__ __launch_bounds__(256) void scan_block(int* __restrict__ partials, int nb,
                                                  float* __restrict__ loss,
                                                  const float* __restrict__ labelsum,
                                                  float* __restrict__ pmsum) {
  __shared__ int tmp[256];
  __shared__ int carry;
  int tid = threadIdx.x;
  {
    float v = 0.f;
    for (int i = tid; i < NBLK; i += 256) v += labelsum[i];
#pragma unroll
    for (int o = 32; o > 0; o >>= 1) v += __shfl_down(v, o);
    __shared__ float sl[4];
    if ((tid & 63) == 0) sl[tid >> 6] = v;
    __syncthreads();
    if (tid == 0) *pmsum = sl[0] + sl[1] + sl[2] + sl[3];
  }
  if (tid == 0) { carry = 0; *loss = 0.f; }
  __syncthreads();
  for (int base = 0; base < nb; base += 256) {
    int i = base + tid;
    int v = (i < nb) ? partials[i] : 0;
    tmp[tid] = v;
    __syncthreads();
    int incl = v;
    for (int o = 1; o < 256; o <<= 1) {
      int t = (tid >= o) ? tmp[tid - o] : 0;
      __syncthreads();
      incl += t;
      tmp[tid] = incl;
      __syncthreads();
    }
    int total = tmp[255];
    int c = carry;
    if (i < nb) partials[i] = c + incl - v;  // exclusive
    __syncthreads();
    if (tid == 0) carry = c + total;
    __syncthreads();
  }
}

__global__ __launch_bounds__(256) void scan_final_t(const int* __restrict__ histG,
                                                    const int* __restrict__ partials,
                                                    int* __restrict__ scannedG,
                                                    int total, int NBUCK) {
  __shared__ int tmp[256];
  int tid = threadIdx.x;
  int i = blockIdx.x * 256 + tid;
  int bucket = i >> NBLK_SHIFT, blk = i & (NBLK - 1);
  int v = (i < total) ? histG[blk * NBUCK + bucket] : 0;
  tmp[tid] = v;
  __syncthreads();
  int incl = v;
  for (int o = 1; o < 256; o <<= 1) {
    int t = (tid >= o) ? tmp[tid - o] : 0;
    __syncthreads();
    incl += t;
    tmp[tid] = incl;
    __syncthreads();
  }
  if (i < total) scannedG[blk * NBUCK + bucket] = partials[blockIdx.x] + incl - v;
}

// ---------------- P3: bucket-partition scatter (LDS cursors, no global atomics) ----------------

__global__ __launch_bounds__(256) void scatter_kernel(const int* __restrict__ rows,
                                                      const int* __restrict__ cols,
                                                      const int* __restrict__ scannedG,
                                                      unsigned int* __restrict__ packed,
                                                      int E, int NBUCK) {
  __shared__ int cur[512];
  for (int i = threadIdx.x; i < NBUCK; i += 256)
    cur[i] = scannedG[blockIdx.x * NBUCK + i];
  __syncthreads();
  int chunk = (E + NBLK - 1) / NBLK;
  int s = blockIdx.x * chunk;
  int e = min(E, s + chunk);
  for (int i = s + threadIdx.x; i < e; i += 256) {
    int c = cols[i];
    int r = rows[i];
    int pos = atomicAdd(&cur[c >> 8], 1);
    packed[pos] = ((unsigned int)(c & 255) << 24) | (unsigned int)r;
  }
}

// ---------------- P4: per-bucket CSR finalize (1024 threads/block) ----------------

__global__ __launch_bounds__(1024) void csr_finalize(const unsigned int* __restrict__ packed,
                                                     const int* __restrict__ scannedG,
                                                     int* __restrict__ sorted_src,
                                                     int* __restrict__ offsets,
                                                     float* __restrict__ dinv,
                                                     int N, int E, int NBUCK) {
  __shared__ int h[256];
  __shared__ int tmp[256];
  __shared__ int cur[256];
  int b = blockIdx.x;
  int tid = threadIdx.x;
  int base = scannedG[b];
  int end = (b + 1 < NBUCK) ? scannedG[b + 1] : E;
  if (tid < 256) h[tid] = 0;
  __syncthreads();
  for (int i = base + tid; i < end; i += 1024)
    atomicAdd(&h[packed[i] >> 24], 1);
  __syncthreads();
  if (tid < 256) {
    int v = h[tid];
    tmp[tid] = v;
  }
  __syncthreads();
  if (tid < 256) {
    int v = h[tid];
    int incl = v;
    for (int o = 1; o < 256; o <<= 1) {
      int t = (tid >= o) ? tmp[tid - o] : 0;
      __syncthreads();
      incl += t;
      tmp[tid] = incl;
      __syncthreads();
    }
    int excl = incl - v;
    int node = b * 256 + tid;
    if (node < N) {
      offsets[node] = base + excl;
      dinv[node] = rsqrtf((float)(v + 1));  // +1 self loop
    }
    cur[tid] = base + excl;
    if (b == NBUCK - 1 && tid == 0) offsets[N] = E;
  } else {
    for (int o = 1; o < 256; o <<= 1) { __syncthreads(); __syncthreads(); }
  }
  __syncthreads();
  for (int i = base + tid; i < end; i += 1024) {
    unsigned int p = packed[i];
    int pos = atomicAdd(&cur[p >> 24], 1);
    sorted_src[pos] = (int)(p & 0xFFFFFFu);
  }
}

// ---------------- MFMA GEMM (layer 1 only): A_fp8[N,64] = (x[N,128] @ W1) * dinv[n] ----------------

__global__ __launch_bounds__(256) void mfma_gemm1(const float* __restrict__ xv,
                                                  const unsigned short* __restrict__ Wt,
                                                  const float* __restrict__ dinv,
                                                  unsigned char* __restrict__ out, int N) {
  const int K = 128;
  __shared__ unsigned short tile[4][16 * 68];
  int w = threadIdx.x >> 6, lane = threadIdx.x & 63;
  int m = lane & 15, quad = lane >> 4;
  int m0 = blockIdx.x * 64 + w * 16;
  int rowA = m0 + m;
  bool rowOK = rowA < N;
  f32x4 acc[4] = {{0.f,0.f,0.f,0.f},{0.f,0.f,0.f,0.f},{0.f,0.f,0.f,0.f},{0.f,0.f,0.f,0.f}};
#pragma unroll
  for (int kc = 0; kc < K / 32; ++kc) {
    short8 a = {0, 0, 0, 0, 0, 0, 0, 0};
    if (rowOK) {
      const float* hp = xv + (size_t)rowA * K + kc * 32 + quad * 8;
      float4 p0 = ((const float4*)hp)[0];
      float4 p1 = ((const float4*)hp)[1];
      a[0] = (short)f2bf(p0.x); a[1] = (short)f2bf(p0.y);
      a[2] = (short)f2bf(p0.z); a[3] = (short)f2bf(p0.w);
      a[4] = (short)f2bf(p1.x); a[5] = (short)f2bf(p1.y);
      a[6] = (short)f2bf(p1.z); a[7] = (short)f2bf(p1.w);
    }
#pragma unroll
    for (int t = 0; t < 4; ++t) {
      short8 b = *(const short8*)(Wt + (size_t)(t * 16 + m) * K + kc * 32 + quad * 8);
      acc[t] = __builtin_amdgcn_mfma_f32_16x16x32_bf16(a, b, acc[t], 0, 0, 0);
    }
  }
  unsigned short* tw = tile[w];
#pragma unroll
  for (int r = 0; r < 4; ++r) {
    int row = quad * 4 + r;
    int gr = m0 + row;
    float dv = dinv[gr < N ? gr : 0];
#pragma unroll
    for (int t = 0; t < 4; ++t)
      tw[row * 68 + t * 16 + m] = f2bf(acc[t][r] * dv);
  }
#pragma unroll
  for (int p = 0; p < 4; ++p) {
    int row = p * 4 + (lane >> 4);
    int ch = lane & 15;  // 4-feature chunk
    int gr = m0 + row;
    if (gr < N) {
      uint2 v = *(const uint2*)(tw + row * 68 + ch * 4);
      float f0 = bf2f((unsigned short)(v.x & 0xFFFFu));
      float f1 = bf2f((unsigned short)(v.x >> 16));
      float f2 = bf2f((unsigned short)(v.y & 0xFFFFu));
      float f3 = bf2f((unsigned short)(v.y >> 16));
      int pk = 0;
      pk = __builtin_amdgcn_cvt_pk_fp8_f32(f0, f1, pk, false);
      pk = __builtin_amdgcn_cvt_pk_fp8_f32(f2, f3, pk, true);
      *(unsigned int*)(out + (size_t)gr * 64 + ch * 4) = (unsigned int)pk;
    }
  }
}

// ---------------- gather core: one node per 4-lane quad, 16B/lane, BRANCHLESS + PINNED ----------
// Invalid edge slots clamp to the zero-row (ZR). All 16 uint4 loads issue before any
// convert: sched_barrier(0) forbids the scheduler from interleaving converts into the
// load batch (round-7 evidence: without it, VGPR=52 -> batch serialized ~4-deep).

#define GATHER_CORE(A8in, ZR)                                                    \
  f32x2 a0={0.f,0.f},a1={0.f,0.f},a2={0.f,0.f},a3={0.f,0.f};                     \
  f32x2 a4={0.f,0.f},a5={0.f,0.f},a6={0.f,0.f},a7={0.f,0.f};                     \
  for (int base = s; base < e; base += 16) {                                     \
    int i0 = base + l4 * 4;                                                      \
    int r0 = (i0     < e) ? __builtin_nontemporal_load(sorted_src + i0)     : ZR;\
    int r1 = (i0 + 1 < e) ? __builtin_nontemporal_load(sorted_src + i0 + 1) : ZR;\
    int r2 = (i0 + 2 < e) ? __builtin_nontemporal_load(sorted_src + i0 + 2) : ZR;\
    int r3 = (i0 + 3 < e) ? __builtin_nontemporal_load(sorted_src + i0 + 3) : ZR;\
    int rj[16];                                                                  \
    _Pragma("unroll")                                                            \
    for (int s4 = 0; s4 < 4; ++s4) {                                             \
      rj[s4 * 4 + 0] = __shfl(r0, qbase + s4);                                   \
      rj[s4 * 4 + 1] = __shfl(r1, qbase + s4);                                   \
      rj[s4 * 4 + 2] = __shfl(r2, qbase + s4);                                   \
      rj[s4 * 4 + 3] = __shfl(r3, qbase + s4);                                   \
    }                                                                            \
    uint4 v[16];                                                                 \
    _Pragma("unroll")                                                            \
    for (int t = 0; t < 16; ++t)                                                 \
      v[t] = *(const uint4*)(A8in + ((size_t)(unsigned int)rj[t] << 6) + l4 * 16);\
    __builtin_amdgcn_sched_barrier(0);                                           \
    _Pragma("unroll")                                                            \
    for (int t = 0; t < 16; ++t) {                                               \
      a0 += __builtin_amdgcn_cvt_pk_f32_fp8((int)v[t].x, false);                 \
      a1 += __builtin_amdgcn_cvt_pk_f32_fp8((int)v[t].x, true);                  \
      a2 += __builtin_amdgcn_cvt_pk_f32_fp8((int)v[t].y, false);                 \
      a3 += __builtin_amdgcn_cvt_pk_f32_fp8((int)v[t].y, true);                  \
      a4 += __builtin_amdgcn_cvt_pk_f32_fp8((int)v[t].z, false);                 \
      a5 += __builtin_amdgcn_cvt_pk_f32_fp8((int)v[t].z, true);                  \
      a6 += __builtin_amdgcn_cvt_pk_f32_fp8((int)v[t].w, false);                 \
      a7 += __builtin_amdgcn_cvt_pk_f32_fp8((int)v[t].w, true);                  \
    }                                                                            \
  }

// ---------------- FUSED: gather-aggregate + bias + ReLU + (h @ Wnext)*dinv -> A8out ----------------
// 64 nodes/block (4-lane quads). h staged in LDS [64][72] bf16, 32 MFMAs/block.
// __launch_bounds__(256,4): VGPR cap 128 so the 16-load gather batch stays in regs.

__global__ __launch_bounds__(256, 4) void agg_gemm(const unsigned char* __restrict__ A8in,
                                                   const int* __restrict__ offsets,
                                                   const int* __restrict__ sorted_src,
                                                   const float* __restrict__ dinv,
                                                   const float* __restrict__ bias,
                                                   const unsigned short* __restrict__ Wt,
                                                   unsigned char* __restrict__ A8out,
                                                   int N, int ZR) {
  __shared__ unsigned short hl[64 * 72];
  int lane = threadIdx.x & 63;
  int cl = threadIdx.x >> 2;             // local node 0..63
  int c = blockIdx.x * 64 + cl;
  int l4 = lane & 3;                     // 16B chunk of the 64B row
  int qbase = lane & 60;
  bool ok = c < N;
  int s = 0, e = 0;
  float dc = 0.f;
  uint4 svr = {0u, 0u, 0u, 0u};
  if (ok) {
    s = offsets[c]; e = offsets[c + 1];
    dc = dinv[c];
    svr = *(const uint4*)(A8in + ((size_t)c << 6) + l4 * 16);
  }
  GATHER_CORE(A8in, ZR)
  // h = relu(agg*dc + b) -> bf16 LDS row (zeros for invalid rows)
  {
    short8 w0 = {0,0,0,0,0,0,0,0}, w1 = {0,0,0,0,0,0,0,0};
    if (ok) {
      a0 += __builtin_amdgcn_cvt_pk_f32_fp8((int)svr.x, false);
      a1 += __builtin_amdgcn_cvt_pk_f32_fp8((int)svr.x, true);
      a2 += __builtin_amdgcn_cvt_pk_f32_fp8((int)svr.y, false);
      a3 += __builtin_amdgcn_cvt_pk_f32_fp8((int)svr.y, true);
      a4 += __builtin_amdgcn_cvt_pk_f32_fp8((int)svr.z, false);
      a5 += __builtin_amdgcn_cvt_pk_f32_fp8((int)svr.z, true);
      a6 += __builtin_amdgcn_cvt_pk_f32_fp8((int)svr.w, false);
      a7 += __builtin_amdgcn_cvt_pk_f32_fp8((int)svr.w, true);
      float accf[16] = {a0[0],a0[1],a1[0],a1[1],a2[0],a2[1],a3[0],a3[1],
                        a4[0],a4[1],a5[0],a5[1],a6[0],a6[1],a7[0],a7[1]};
      const float* bp = bias + l4 * 16;
#pragma unroll
      for (int q = 0; q < 8; ++q) {
        float v = fmaf(accf[q], dc, bp[q]);
        w0[q] = (short)f2bf(v > 0.f ? v : 0.f);
      }
#pragma unroll
      for (int q = 0; q < 8; ++q) {
        float v = fmaf(accf[8 + q], dc, bp[8 + q]);
        w1[q] = (short)f2bf(v > 0.f ? v : 0.f);
      }
    }
    short8* dst = (short8*)(hl + cl * 72 + l4 * 16);
    dst[0] = w0; dst[1] = w1;
  }
  __syncthreads();
  // MFMA: wave wv handles rows wv*16..+15, all 64 cols, K=64
  int wv = threadIdx.x >> 6;
  int m = lane & 15, quad = lane >> 4;
  int rbase = wv * 16;
  f32x4 acc2[4] = {{0.f,0.f,0.f,0.f},{0.f,0.f,0.f,0.f},{0.f,0.f,0.f,0.f},{0.f,0.f,0.f,0.f}};
#pragma unroll
  for (int kc = 0; kc < 2; ++kc) {
    short8 a = *(const short8*)(hl + (rbase + m) * 72 + kc * 32 + quad * 8);
#pragma unroll
    for (int t = 0; t < 4; ++t) {
      short8 b = *(const short8*)(Wt + (size_t)(t * 16 + m) * 64 + kc * 32 + quad * 8);
      acc2[t] = __builtin_amdgcn_mfma_f32_16x16x32_bf16(a, b, acc2[t], 0, 0, 0);
    }
  }
  __syncthreads();   // all reads of hl done; reuse as output tile
#pragma unroll
  for (int r = 0; r < 4; ++r) {
    int row = rbase + quad * 4 + r;
    int gr = blockIdx.x * 64 + row;
    float dv = dinv[gr < N ? gr : 0];
#pragma unroll
    for (int t = 0; t < 4; ++t)
      hl[row * 72 + t * 16 + m] = f2bf(acc2[t][r] * dv);
  }
  __syncthreads();
  // fp8 pack: 64 rows x 16 chunks = 1024 items over 256 threads, coalesced
#pragma unroll
  for (int u = 0; u < 4; ++u) {
    int id = u * 256 + threadIdx.x;
    int row = id >> 4, ch = id & 15;
    int gr = blockIdx.x * 64 + row;
    if (gr < N) {
      uint2 v = *(const uint2*)(hl + row * 72 + ch * 4);
      float f0 = bf2f((unsigned short)(v.x & 0xFFFFu));
      float f1 = bf2f((unsigned short)(v.x >> 16));
      float f2 = bf2f((unsigned short)(v.y & 0xFFFFu));
      float f3 = bf2f((unsigned short)(v.y >> 16));
      int pk = 0;
      pk = __builtin_amdgcn_cvt_pk_fp8_f32(f0, f1, pk, false);
      pk = __builtin_amdgcn_cvt_pk_fp8_f32(f2, f3, pk, true);
      *(unsigned int*)(A8out + (size_t)gr * 64 + ch * 4) = (unsigned int)pk;
    }
  }
}

// ---------------- FUSED: gather-aggregate (layer 3) + MLP head + sigmoid + BCE ----------------

__global__ __launch_bounds__(256, 4) void agg_head(const unsigned char* __restrict__ A8in,
                                                   const int* __restrict__ offsets,
                                                   const int* __restrict__ sorted_src,
                                                   const float* __restrict__ dinv,
                                                   const float* __restrict__ bias,
                                                   const float* __restrict__ lW1,
                                                   const float* __restrict__ lb1,
                                                   const float* __restrict__ lW2,
                                                   const float* __restrict__ lb2,
                                                   const int* __restrict__ labels,
                                                   const float* __restrict__ pmsum,
                                                   float* __restrict__ p,
                                                   float* __restrict__ loss,
                                                   int N, int ZR) {
  int lane = threadIdx.x & 63;
  int cl = threadIdx.x >> 2;
  int c = blockIdx.x * 64 + cl;
  int l4 = lane & 3;
  int qbase = lane & 60;
  bool ok = c < N;
  int s = 0, e = 0;
  float dc = 0.f;
  uint4 svr = {0u, 0u, 0u, 0u};
  if (ok) {
    s = offsets[c]; e = offsets[c + 1];
    dc = dinv[c];
    svr = *(const uint4*)(A8in + ((size_t)c << 6) + l4 * 16);
  }
  GATHER_CORE(A8in, ZR)
  float contrib = 0.f;
  {
    a0 += __builtin_amdgcn_cvt_pk_f32_fp8((int)svr.x, false);
    a1 += __builtin_amdgcn_cvt_pk_f32_fp8((int)svr.x, true);
    a2 += __builtin_amdgcn_cvt_pk_f32_fp8((int)svr.y, false);
    a3 += __builtin_amdgcn_cvt_pk_f32_fp8((int)svr.y, true);
    a4 += __builtin_amdgcn_cvt_pk_f32_fp8((int)svr.z, false);
    a5 += __builtin_amdgcn_cvt_pk_f32_fp8((int)svr.z, true);
    a6 += __builtin_amdgcn_cvt_pk_f32_fp8((int)svr.w, false);
    a7 += __builtin_amdgcn_cvt_pk_f32_fp8((int)svr.w, true);
    float accf[16] = {a0[0],a0[1],a1[0],a1[1],a2[0],a2[1],a3[0],a3[1],
                      a4[0],a4[1],a5[0],a5[1],a6[0],a6[1],a7[0],a7[1]};
    const float* bp = bias + l4 * 16;
    float hq[16];
#pragma unroll
    for (int q = 0; q < 16; ++q) {
      float v = fmaf(accf[q], dc, bp[q]);
      hq[q] = v > 0.f ? v : 0.f;
    }
    // per-lane partial contraction over this lane's 16 feats
    float acc8[8] = {0.f,0.f,0.f,0.f,0.f,0.f,0.f,0.f};
#pragma unroll
    for (int q = 0; q < 16; ++q) {
      int k = l4 * 16 + q;
#pragma unroll
      for (int j = 0; j < 8; ++j) acc8[j] = fmaf(hq[q], lW1[k * 8 + j], acc8[j]);
    }
    // quad reduce (lanes l^1, l^2 are in the same quad)
#pragma unroll
    for (int j = 0; j < 8; ++j) {
      acc8[j] += __shfl_xor(acc8[j], 1);
      acc8[j] += __shfl_xor(acc8[j], 2);
    }
    if (ok && l4 == 0) {
      float sv = lb2[0];
#pragma unroll
      for (int j = 0; j < 8; ++j) {
        float a = acc8[j] + lb1[j];
        a = a > 0.f ? a : 0.f;
        sv = fmaf(a, lW2[j], sv);
      }
      float pv = 1.0f / (1.0f + expf(-sv));
      p[c] = pv;
      float pm = *pmsum / (float)N;
      float y = (float)labels[c];
      float w = y * (1.f - pm) + (1.f - y) * pm;
      float pc = fminf(fmaxf(pv, 1e-7f), 1.f - 1e-7f);
      float bce = -(y * logf(pc) + (1.f - y) * logf(1.f - pc));
      contrib = w * bce / (float)N;
    }
  }
#pragma unroll
  for (int o = 32; o > 0; o >>= 1) contrib += __shfl_down(contrib, o);
  __shared__ float sh[4];
  int wv = threadIdx.x >> 6;
  if (lane == 0) sh[wv] = contrib;
  __syncthreads();
  if (threadIdx.x == 0) atomicAdd(loss, sh[0] + sh[1] + sh[2] + sh[3]);
}

// ---------------- launch ----------------

extern "C" void kernel_launch(void* const* d_in, const int* in_sizes, int n_in,
                              void* d_out, int out_size, void* d_ws, size_t ws_size,
                              hipStream_t stream) {
  const float* x      = (const float*)d_in[0];
  const int*   ei     = (const int*)d_in[1];
  const int*   labels = (const int*)d_in[2];
  const float* W1 = (const float*)d_in[3];
  const float* b1 = (const float*)d_in[4];
  const float* W2 = (const float*)d_in[5];
  const float* b2 = (const float*)d_in[6];
  const float* W3 = (const float*)d_in[7];
  const float* b3 = (const float*)d_in[8];
  const float* lW1 = (const float*)d_in[9];
  const float* lb1 = (const float*)d_in[10];
  const float* lW2 = (const float*)d_in[11];
  const float* lb2 = (const float*)d_in[12];

  int N = in_sizes[2];            // labels: [N,1]
  int E = in_sizes[1] / 2;        // edge_index: [2,E]
  const int* rows = ei;           // sources
  const int* cols = ei + E;       // targets (aggregation)

  int Npad = (N + 63) & ~63;
  int NBUCK = (N + 255) >> 8;               // 256-node buckets
  int totalH = NBUCK * NBLK;                // histogram entries
  int nb2 = (totalH + 255) / 256;

  // workspace layout: A8 buffers have one extra zero-row at index Npad (gather clamp)
  size_t a8stride = (size_t)Npad * 64 + 256;
  char* ws = (char*)d_ws;
  unsigned char*  A8a = (unsigned char*)ws;
  unsigned char*  A8b = (unsigned char*)(ws + a8stride);
  unsigned short* Wt1 = (unsigned short*)(ws + (size_t)Npad * 192); // 64*128
  unsigned short* Wt2 = Wt1 + 64 * 128;                 // 64*64
  unsigned short* Wt3 = Wt2 + 64 * 64;                  // 64*64
  float* dinv     = (float*)(Wt3 + 64 * 64);            // N
  int*   offsets  = (int*)(dinv + N);                   // N+1
  int*   histG    = offsets + N + 1;                    // NBLK*NBUCK
  int*   scanned  = histG + totalH;                     // NBLK*NBUCK
  unsigned int* packed = (unsigned int*)(scanned + totalH);  // E
  int*   sorted   = (int*)(packed + E);                 // E
  int*   partials = sorted + E;                         // nb2
  float* pmsum    = (float*)(partials + nb2);           // 1
  float* labelsum = pmsum + 1;                          // NBLK

  float* loss = (float*)d_out;
  float* p    = (float*)d_out + 1;

  int gemmBlocks = Npad / 64;
  int aggBlocks  = (N + 63) / 64;
  int ZR = Npad;                   // zero-row index

  // ---- atomic-free CSR build (+ Wt transpose, zero-rows & label-sum folded into hist) ----
  hist_kernel<<<NBLK, 256, 0, stream>>>(cols, histG, labels, labelsum,
                                        W1, W2, W3, Wt1, Wt2, Wt3,
                                        A8a + (size_t)Npad * 64, A8b + (size_t)Npad * 64,
                                        E, N, NBUCK);
  scan_partials_t<<<nb2, 256, 0, stream>>>(histG, partials, totalH, NBUCK);
  scan_block<<<1, 256, 0, stream>>>(partials, nb2, loss, labelsum, pmsum);
  scan_final_t<<<nb2, 256, 0, stream>>>(histG, partials, scanned, totalH, NBUCK);
  scatter_kernel<<<NBLK, 256, 0, stream>>>(rows, cols, scanned, packed, E, NBUCK);
  csr_finalize<<<NBUCK, 1024, 0, stream>>>(packed, scanned, sorted, offsets, dinv, N, E, NBUCK);

  // ---- layer 1 GEMM (K=128, fp32 x converted in-flight) ----
  mfma_gemm1<<<gemmBlocks, 256, 0, stream>>>(x, Wt1, dinv, A8a, N);

  // ---- fused layers: agg1+gemm2, agg2+gemm3, agg3+head ----
  agg_gemm<<<aggBlocks, 256, 0, stream>>>(A8a, offsets, sorted, dinv, b1, Wt2, A8b, N, ZR);
  agg_gemm<<<aggBlocks, 256, 0, stream>>>(A8b, offsets, sorted, dinv, b2, Wt3, A8a, N, ZR);
  agg_head<<<aggBlocks, 256, 0, stream>>>(A8a, offsets, sorted, dinv, b3,
                                          lW1, lb1, lW2, lb2, labels, pmsum, p, loss, N, ZR);
}

// Round 9
// 277.157 us; speedup vs baseline: 4.6152x; 1.0047x over previous
//
#include <hip/hip_runtime.h>
#include <cstdint>
#include <cstddef>

typedef __attribute__((ext_vector_type(8))) short short8;
typedef __attribute__((ext_vector_type(4))) float f32x4;
typedef __attribute__((ext_vector_type(2))) float f32x2;

#define NBLK 512        // edge-chunk blocks for hist/scatter (pow2, = 8 XCDs * 64)
#define NBLK_SHIFT 9

// chunk permutation: adjacent chunks (adjacent scan runs in packed[]) map to the
// SAME XCD (blockIdx round-robins XCDs) -> packed-line sharing stays intra-XCD.
__device__ inline int chunk_of_block(int bid) { return ((bid & 7) << 6) | (bid >> 3); }

__device__ inline unsigned short f2bf(float f) {
  union { float f; unsigned int u; } x; x.f = f;
  unsigned int r = x.u + 0x7FFFu + ((x.u >> 16) & 1u);  // round-to-nearest-even
  return (unsigned short)(r >> 16);
}
__device__ inline float bf2f(unsigned short s) {
  union { unsigned int u; float f; } x; x.u = ((unsigned int)s) << 16;
  return x.f;
}

// ---------------- P1: per-block bucket histogram (LDS atomics only) ----------------
// blocks 0..2 transpose W1..W3; block 3 zeroes the gather zero-rows of A8a/A8b.

__global__ __launch_bounds__(256) void hist_kernel(const int* __restrict__ cols,
                                                   int* __restrict__ histG,
                                                   const int* __restrict__ labels,
                                                   float* __restrict__ labelsum,
                                                   const float* __restrict__ W1,
                                                   const float* __restrict__ W2,
                                                   const float* __restrict__ W3,
                                                   unsigned short* __restrict__ Wt1,
                                                   unsigned short* __restrict__ Wt2,
                                                   unsigned short* __restrict__ Wt3,
                                                   unsigned char* __restrict__ zrow_a,
                                                   unsigned char* __restrict__ zrow_b,
                                                   int E, int N, int NBUCK) {
  __shared__ int h[512];
  if (blockIdx.x < 3) {
    const float* W; unsigned short* Wt; int K;
    if (blockIdx.x == 0)      { W = W1; Wt = Wt1; K = 128; }
    else if (blockIdx.x == 1) { W = W2; Wt = Wt2; K = 64; }
    else                      { W = W3; Wt = Wt3; K = 64; }
    int total = K * 64;
    for (int i = threadIdx.x; i < total; i += 256) {
      int n = i / K, k = i - n * K;  // Wt[n][k] = W[k][n]
      Wt[i] = f2bf(W[k * 64 + n]);
    }
  } else if (blockIdx.x == 3 && threadIdx.x < 32) {
    if (threadIdx.x < 16) ((unsigned int*)zrow_a)[threadIdx.x] = 0u;
    else                  ((unsigned int*)zrow_b)[threadIdx.x - 16] = 0u;
  }
  {
    int chunkL = (N + NBLK - 1) / NBLK;
    int ls = blockIdx.x * chunkL;
    int le = min(N, ls + chunkL);
    float v = 0.f;
    for (int i = ls + threadIdx.x; i < le; i += 256) v += (float)labels[i];
#pragma unroll
    for (int o = 32; o > 0; o >>= 1) v += __shfl_down(v, o);
    __shared__ float sl[4];
    if ((threadIdx.x & 63) == 0) sl[threadIdx.x >> 6] = v;
    __syncthreads();
    if (threadIdx.x == 0) labelsum[blockIdx.x] = sl[0] + sl[1] + sl[2] + sl[3];
  }
  for (int i = threadIdx.x; i < NBUCK; i += 256) h[i] = 0;
  __syncthreads();
  int cchunk = chunk_of_block(blockIdx.x);
  int chunk = (E + NBLK - 1) / NBLK;
  int s = cchunk * chunk;
  int e = min(E, s + chunk);
  for (int i = s + threadIdx.x; i < e; i += 256) atomicAdd(&h[cols[i] >> 8], 1);
  __syncthreads();
  for (int i = threadIdx.x; i < NBUCK; i += 256)
    histG[cchunk * NBUCK + i] = h[i];
}

// ---------------- P2: scan of NBUCK*NBLK counts, bucket-major logical order ----------------

__global__ __launch_bounds__(256) void scan_partials_t(const int* __restrict__ histG,
                                                       int* __restrict__ partials,
                                                       int total, int NBUCK) {
  int i = blockIdx.x * 256 + threadIdx.x;
  int v = 0;
  if (i < total) {
    int bucket = i >> NBLK_SHIFT, blk = i & (NBLK - 1);
    v = histG[blk * NBUCK + bucket];
  }
#pragma unroll
  for (int o = 32; o > 0; o >>= 1) v += __shfl_down(v, o);
  __shared__ int s[4];
  if ((threadIdx.x & 63) == 0) s[threadIdx.x >> 6] = v;
  __syncthreads();
  if (threadIdx.x == 0) partials[blockIdx.x] = s[0] + s[1] + s[2] + s[3];
}

__global__ __launch_bounds__(256) void scan_block(int* __restrict__ partials, int nb,
                                                  float* __restrict__ loss,
                                                  const float* __restrict__ labelsum,
                                                  float* __restrict__ pmsum) {
  __shared__ int tmp[256];
  __shared__ int carry;
  int tid = threadIdx.x;
  {
    float v = 0.f;
    for (int i = tid; i < NBLK; i += 256) v += labelsum[i];
#pragma unroll
    for (int o = 32; o > 0; o >>= 1) v += __shfl_down(v, o);
    __shared__ float sl[4];
    if ((tid & 63) == 0) sl[tid >> 6] = v;
    __syncthreads();
    if (tid == 0) *pmsum = sl[0] + sl[1] + sl[2] + sl[3];
  }
  if (tid == 0) { carry = 0; *loss = 0.f; }
  __syncthreads();
  for (int base = 0; base < nb; base += 256) {
    int i = base + tid;
    int v = (i < nb) ? partials[i] : 0;
    tmp[tid] = v;
    __syncthreads();
    int incl = v;
    for (int o = 1; o < 256; o <<= 1) {
      int t = (tid >= o) ? tmp[tid - o] : 0;
      __syncthreads();
      incl += t;
      tmp[tid] = incl;
      __syncthreads();
    }
    int total = tmp[255];
    int c = carry;
    if (i < nb) partials[i] = c + incl - v;  // exclusive
    __syncthreads();
    if (tid == 0) carry = c + total;
    __syncthreads();
  }
}

__global__ __launch_bounds__(256) void scan_final_t(const int* __restrict__ histG,
                                                    const int* __restrict__ partials,
                                                    int* __restrict__ scannedG,
                                                    int total, int NBUCK) {
  __shared__ int tmp[256];
  int tid = threadIdx.x;
  int i = blockIdx.x * 256 + tid;
  int bucket = i >> NBLK_SHIFT, blk = i & (NBLK - 1);
  int v = (i < total) ? histG[blk * NBUCK + bucket] : 0;
  tmp[tid] = v;
  __syncthreads();
  int incl = v;
  for (int o = 1; o < 256; o <<= 1) {
    int t = (tid >= o) ? tmp[tid - o] : 0;
    __syncthreads();
    incl += t;
    tmp[tid] = incl;
    __syncthreads();
  }
  if (i < total) scannedG[blk * NBUCK + bucket] = partials[blockIdx.x] + incl - v;
}

// ---------------- P3: bucket-partition scatter (LDS cursors, no global atomics) ----------------

__global__ __launch_bounds__(256) void scatter_kernel(const int* __restrict__ rows,
                                                      const int* __restrict__ cols,
                                                      const int* __restrict__ scannedG,
                                                      unsigned int* __restrict__ packed,
                                                      int E, int NBUCK) {
  __shared__ int cur[512];
  int cchunk = chunk_of_block(blockIdx.x);
  for (int i = threadIdx.x; i < NBUCK; i += 256)
    cur[i] = scannedG[cchunk * NBUCK + i];
  __syncthreads();
  int chunk = (E + NBLK - 1) / NBLK;
  int s = cchunk * chunk;
  int e = min(E, s + chunk);
  for (int i = s + threadIdx.x; i < e; i += 256) {
    int c = cols[i];
    int r = rows[i];
    int pos = atomicAdd(&cur[c >> 8], 1);
    packed[pos] = ((unsigned int)(c & 255) << 24) | (unsigned int)r;
  }
}

// ---------------- P4: per-bucket CSR finalize + FUSED layer-1 GEMM ----------------
// After finalize, this bucket's 256 nodes have dinv in LDS -> run their
// A8a = (x @ W1)*dinv tiles in the same kernel (16 waves, 4 tiles of 64 rows).

__global__ __launch_bounds__(1024) void csr_finalize_gemm1(const unsigned int* __restrict__ packed,
                                                           const int* __restrict__ scannedG,
                                                           int* __restrict__ sorted_src,
                                                           int* __restrict__ offsets,
                                                           float* __restrict__ dinv,
                                                           const float* __restrict__ xv,
                                                           const unsigned short* __restrict__ Wt,
                                                           unsigned char* __restrict__ out,
                                                           int N, int E, int NBUCK) {
  __shared__ int h[256];
  __shared__ int tmp[256];
  __shared__ int cur[256];
  __shared__ float sdinv[256];
  __shared__ unsigned short gtile[16][16 * 68];   // 34.8 KB gemm staging
  int b = blockIdx.x;
  int tid = threadIdx.x;
  int base = scannedG[b];
  int end = (b + 1 < NBUCK) ? scannedG[b + 1] : E;
  if (tid < 256) h[tid] = 0;
  __syncthreads();
  for (int i = base + tid; i < end; i += 1024)
    atomicAdd(&h[packed[i] >> 24], 1);
  __syncthreads();
  if (tid < 256) {
    int v = h[tid];
    tmp[tid] = v;
  }
  __syncthreads();
  if (tid < 256) {
    int v = h[tid];
    int incl = v;
    for (int o = 1; o < 256; o <<= 1) {
      int t = (tid >= o) ? tmp[tid - o] : 0;
      __syncthreads();
      incl += t;
      tmp[tid] = incl;
      __syncthreads();
    }
    int excl = incl - v;
    int node = b * 256 + tid;
    float dv = rsqrtf((float)(v + 1));  // +1 self loop
    if (node < N) {
      offsets[node] = base + excl;
      dinv[node] = dv;
    }
    sdinv[tid] = dv;
    cur[tid] = base + excl;
    if (b == NBUCK - 1 && tid == 0) offsets[N] = E;
  } else {
    for (int o = 1; o < 256; o <<= 1) { __syncthreads(); __syncthreads(); }
  }
  __syncthreads();
  for (int i = base + tid; i < end; i += 1024) {
    unsigned int p = packed[i];
    int pos = atomicAdd(&cur[p >> 24], 1);
    sorted_src[pos] = (int)(p & 0xFFFFFFu);
  }
  // ---- fused layer-1 GEMM for this bucket's 256 nodes (no barrier needed:
  // gemm reads nothing the scatter loop writes; sdinv was fenced above) ----
  {
    const int K = 128;
    int wv = tid >> 6;                 // wave 0..15
    int lane = tid & 63;
    int m = lane & 15, quad = lane >> 4;
    int lrow0 = wv * 16;               // local row base in bucket (0..240)
    int m0 = b * 256 + lrow0;
    int rowA = m0 + m;
    bool rowOK = rowA < N;
    f32x4 acc[4] = {{0.f,0.f,0.f,0.f},{0.f,0.f,0.f,0.f},{0.f,0.f,0.f,0.f},{0.f,0.f,0.f,0.f}};
#pragma unroll
    for (int kc = 0; kc < K / 32; ++kc) {
      short8 a = {0, 0, 0, 0, 0, 0, 0, 0};
      if (rowOK) {
        const float* hp = xv + (size_t)rowA * K + kc * 32 + quad * 8;
        float4 p0 = ((const float4*)hp)[0];
        float4 p1 = ((const float4*)hp)[1];
        a[0] = (short)f2bf(p0.x); a[1] = (short)f2bf(p0.y);
        a[2] = (short)f2bf(p0.z); a[3] = (short)f2bf(p0.w);
        a[4] = (short)f2bf(p1.x); a[5] = (short)f2bf(p1.y);
        a[6] = (short)f2bf(p1.z); a[7] = (short)f2bf(p1.w);
      }
#pragma unroll
      for (int t = 0; t < 4; ++t) {
        short8 bb = *(const short8*)(Wt + (size_t)(t * 16 + m) * K + kc * 32 + quad * 8);
        acc[t] = __builtin_amdgcn_mfma_f32_16x16x32_bf16(a, bb, acc[t], 0, 0, 0);
      }
    }
    unsigned short* tw = gtile[wv];
#pragma unroll
    for (int r = 0; r < 4; ++r) {
      int row = quad * 4 + r;
      float dv = sdinv[lrow0 + row];
#pragma unroll
      for (int t = 0; t < 4; ++t)
        tw[row * 68 + t * 16 + m] = f2bf(acc[t][r] * dv);
    }
#pragma unroll
    for (int p = 0; p < 4; ++p) {
      int row = p * 4 + (lane >> 4);
      int ch = lane & 15;  // 4-feature chunk
      int gr = m0 + row;
      if (gr < N) {
        uint2 v = *(const uint2*)(tw + row * 68 + ch * 4);
        float f0 = bf2f((unsigned short)(v.x & 0xFFFFu));
        float f1 = bf2f((unsigned short)(v.x >> 16));
        float f2 = bf2f((unsigned short)(v.y & 0xFFFFu));
        float f3 = bf2f((unsigned short)(v.y >> 16));
        int pk = 0;
        pk = __builtin_amdgcn_cvt_pk_fp8_f32(f0, f1, pk, false);
        pk = __builtin_amdgcn_cvt_pk_fp8_f32(f2, f3, pk, true);
        *(unsigned int*)(out + (size_t)gr * 64 + ch * 4) = (unsigned int)pk;
      }
    }
  }
}

// ---------------- gather core: one node per 4-lane quad, 16B/lane, BRANCHLESS + PINNED ----------

#define GATHER_CORE(A8in, ZR)                                                    \
  f32x2 a0={0.f,0.f},a1={0.f,0.f},a2={0.f,0.f},a3={0.f,0.f};                     \
  f32x2 a4={0.f,0.f},a5={0.f,0.f},a6={0.f,0.f},a7={0.f,0.f};                     \
  for (int base = s; base < e; base += 16) {                                     \
    int i0 = base + l4 * 4;                                                      \
    int r0 = (i0     < e) ? __builtin_nontemporal_load(sorted_src + i0)     : ZR;\
    int r1 = (i0 + 1 < e) ? __builtin_nontemporal_load(sorted_src + i0 + 1) : ZR;\
    int r2 = (i0 + 2 < e) ? __builtin_nontemporal_load(sorted_src + i0 + 2) : ZR;\
    int r3 = (i0 + 3 < e) ? __builtin_nontemporal_load(sorted_src + i0 + 3) : ZR;\
    int rj[16];                                                                  \
    _Pragma("unroll")                                                            \
    for (int s4 = 0; s4 < 4; ++s4) {                                             \
      rj[s4 * 4 + 0] = __shfl(r0, qbase + s4);                                   \
      rj[s4 * 4 + 1] = __shfl(r1, qbase + s4);                                   \
      rj[s4 * 4 + 2] = __shfl(r2, qbase + s4);                                   \
      rj[s4 * 4 + 3] = __shfl(r3, qbase + s4);                                   \
    }                                                                            \
    uint4 v[16];                                                                 \
    _Pragma("unroll")                                                            \
    for (int t = 0; t < 16; ++t)                                                 \
      v[t] = *(const uint4*)(A8in + ((size_t)(unsigned int)rj[t] << 6) + l4 * 16);\
    __builtin_amdgcn_sched_barrier(0);                                           \
    _Pragma("unroll")                                                            \
    for (int t = 0; t < 16; ++t) {                                               \
      a0 += __builtin_amdgcn_cvt_pk_f32_fp8((int)v[t].x, false);                 \
      a1 += __builtin_amdgcn_cvt_pk_f32_fp8((int)v[t].x, true);                  \
      a2 += __builtin_amdgcn_cvt_pk_f32_fp8((int)v[t].y, false);                 \
      a3 += __builtin_amdgcn_cvt_pk_f32_fp8((int)v[t].y, true);                  \
      a4 += __builtin_amdgcn_cvt_pk_f32_fp8((int)v[t].z, false);                 \
      a5 += __builtin_amdgcn_cvt_pk_f32_fp8((int)v[t].z, true);                  \
      a6 += __builtin_amdgcn_cvt_pk_f32_fp8((int)v[t].w, false);                 \
      a7 += __builtin_amdgcn_cvt_pk_f32_fp8((int)v[t].w, true);                  \
    }                                                                            \
  }

// ---------------- FUSED: gather-aggregate + bias + ReLU + (h @ Wnext)*dinv -> A8out ----------------

__global__ __launch_bounds__(256, 4) void agg_gemm(const unsigned char* __restrict__ A8in,
                                                   const int* __restrict__ offsets,
                                                   const int* __restrict__ sorted_src,
                                                   const float* __restrict__ dinv,
                                                   const float* __restrict__ bias,
                                                   const unsigned short* __restrict__ Wt,
                                                   unsigned char* __restrict__ A8out,
                                                   int N, int ZR) {
  __shared__ unsigned short hl[64 * 72];
  int lane = threadIdx.x & 63;
  int cl = threadIdx.x >> 2;             // local node 0..63
  int c = blockIdx.x * 64 + cl;
  int l4 = lane & 3;                     // 16B chunk of the 64B row
  int qbase = lane & 60;
  bool ok = c < N;
  int s = 0, e = 0;
  float dc = 0.f;
  uint4 svr = {0u, 0u, 0u, 0u};
  if (ok) {
    s = offsets[c]; e = offsets[c + 1];
    dc = dinv[c];
    svr = *(const uint4*)(A8in + ((size_t)c << 6) + l4 * 16);
  }
  GATHER_CORE(A8in, ZR)
  {
    short8 w0 = {0,0,0,0,0,0,0,0}, w1 = {0,0,0,0,0,0,0,0};
    if (ok) {
      a0 += __builtin_amdgcn_cvt_pk_f32_fp8((int)svr.x, false);
      a1 += __builtin_amdgcn_cvt_pk_f32_fp8((int)svr.x, true);
      a2 += __builtin_amdgcn_cvt_pk_f32_fp8((int)svr.y, false);
      a3 += __builtin_amdgcn_cvt_pk_f32_fp8((int)svr.y, true);
      a4 += __builtin_amdgcn_cvt_pk_f32_fp8((int)svr.z, false);
      a5 += __builtin_amdgcn_cvt_pk_f32_fp8((int)svr.z, true);
      a6 += __builtin_amdgcn_cvt_pk_f32_fp8((int)svr.w, false);
      a7 += __builtin_amdgcn_cvt_pk_f32_fp8((int)svr.w, true);
      float accf[16] = {a0[0],a0[1],a1[0],a1[1],a2[0],a2[1],a3[0],a3[1],
                        a4[0],a4[1],a5[0],a5[1],a6[0],a6[1],a7[0],a7[1]};
      const float* bp = bias + l4 * 16;
#pragma unroll
      for (int q = 0; q < 8; ++q) {
        float v = fmaf(accf[q], dc, bp[q]);
        w0[q] = (short)f2bf(v > 0.f ? v : 0.f);
      }
#pragma unroll
      for (int q = 0; q < 8; ++q) {
        float v = fmaf(accf[8 + q], dc, bp[8 + q]);
        w1[q] = (short)f2bf(v > 0.f ? v : 0.f);
      }
    }
    short8* dst = (short8*)(hl + cl * 72 + l4 * 16);
    dst[0] = w0; dst[1] = w1;
  }
  __syncthreads();
  int wv = threadIdx.x >> 6;
  int m = lane & 15, quad = lane >> 4;
  int rbase = wv * 16;
  f32x4 acc2[4] = {{0.f,0.f,0.f,0.f},{0.f,0.f,0.f,0.f},{0.f,0.f,0.f,0.f},{0.f,0.f,0.f,0.f}};
#pragma unroll
  for (int kc = 0; kc < 2; ++kc) {
    short8 a = *(const short8*)(hl + (rbase + m) * 72 + kc * 32 + quad * 8);
#pragma unroll
    for (int t = 0; t < 4; ++t) {
      short8 b = *(const short8*)(Wt + (size_t)(t * 16 + m) * 64 + kc * 32 + quad * 8);
      acc2[t] = __builtin_amdgcn_mfma_f32_16x16x32_bf16(a, b, acc2[t], 0, 0, 0);
    }
  }
  __syncthreads();
#pragma unroll
  for (int r = 0; r < 4; ++r) {
    int row = rbase + quad * 4 + r;
    int gr = blockIdx.x * 64 + row;
    float dv = dinv[gr < N ? gr : 0];
#pragma unroll
    for (int t = 0; t < 4; ++t)
      hl[row * 72 + t * 16 + m] = f2bf(acc2[t][r] * dv);
  }
  __syncthreads();
#pragma unroll
  for (int u = 0; u < 4; ++u) {
    int id = u * 256 + threadIdx.x;
    int row = id >> 4, ch = id & 15;
    int gr = blockIdx.x * 64 + row;
    if (gr < N) {
      uint2 v = *(const uint2*)(hl + row * 72 + ch * 4);
      float f0 = bf2f((unsigned short)(v.x & 0xFFFFu));
      float f1 = bf2f((unsigned short)(v.x >> 16));
      float f2 = bf2f((unsigned short)(v.y & 0xFFFFu));
      float f3 = bf2f((unsigned short)(v.y >> 16));
      int pk = 0;
      pk = __builtin_amdgcn_cvt_pk_fp8_f32(f0, f1, pk, false);
      pk = __builtin_amdgcn_cvt_pk_fp8_f32(f2, f3, pk, true);
      *(unsigned int*)(A8out + (size_t)gr * 64 + ch * 4) = (unsigned int)pk;
    }
  }
}

// ---------------- FUSED: gather-aggregate (layer 3) + MLP head + sigmoid + BCE ----------------

__global__ __launch_bounds__(256, 4) void agg_head(const unsigned char* __restrict__ A8in,
                                                   const int* __restrict__ offsets,
                                                   const int* __restrict__ sorted_src,
                                                   const float* __restrict__ dinv,
                                                   const float* __restrict__ bias,
                                                   const float* __restrict__ lW1,
                                                   const float* __restrict__ lb1,
                                                   const float* __restrict__ lW2,
                                                   const float* __restrict__ lb2,
                                                   const int* __restrict__ labels,
                                                   const float* __restrict__ pmsum,
                                                   float* __restrict__ p,
                                                   float* __restrict__ loss,
                                                   int N, int ZR) {
  int lane = threadIdx.x & 63;
  int cl = threadIdx.x >> 2;
  int c = blockIdx.x * 64 + cl;
  int l4 = lane & 3;
  int qbase = lane & 60;
  bool ok = c < N;
  int s = 0, e = 0;
  float dc = 0.f;
  uint4 svr = {0u, 0u, 0u, 0u};
  if (ok) {
    s = offsets[c]; e = offsets[c + 1];
    dc = dinv[c];
    svr = *(const uint4*)(A8in + ((size_t)c << 6) + l4 * 16);
  }
  GATHER_CORE(A8in, ZR)
  float contrib = 0.f;
  {
    a0 += __builtin_amdgcn_cvt_pk_f32_fp8((int)svr.x, false);
    a1 += __builtin_amdgcn_cvt_pk_f32_fp8((int)svr.x, true);
    a2 += __builtin_amdgcn_cvt_pk_f32_fp8((int)svr.y, false);
    a3 += __builtin_amdgcn_cvt_pk_f32_fp8((int)svr.y, true);
    a4 += __builtin_amdgcn_cvt_pk_f32_fp8((int)svr.z, false);
    a5 += __builtin_amdgcn_cvt_pk_f32_fp8((int)svr.z, true);
    a6 += __builtin_amdgcn_cvt_pk_f32_fp8((int)svr.w, false);
    a7 += __builtin_amdgcn_cvt_pk_f32_fp8((int)svr.w, true);
    float accf[16] = {a0[0],a0[1],a1[0],a1[1],a2[0],a2[1],a3[0],a3[1],
                      a4[0],a4[1],a5[0],a5[1],a6[0],a6[1],a7[0],a7[1]};
    const float* bp = bias + l4 * 16;
    float hq[16];
#pragma unroll
    for (int q = 0; q < 16; ++q) {
      float v = fmaf(accf[q], dc, bp[q]);
      hq[q] = v > 0.f ? v : 0.f;
    }
    float acc8[8] = {0.f,0.f,0.f,0.f,0.f,0.f,0.f,0.f};
#pragma unroll
    for (int q = 0; q < 16; ++q) {
      int k = l4 * 16 + q;
#pragma unroll
      for (int j = 0; j < 8; ++j) acc8[j] = fmaf(hq[q], lW1[k * 8 + j], acc8[j]);
    }
#pragma unroll
    for (int j = 0; j < 8; ++j) {
      acc8[j] += __shfl_xor(acc8[j], 1);
      acc8[j] += __shfl_xor(acc8[j], 2);
    }
    if (ok && l4 == 0) {
      float sv = lb2[0];
#pragma unroll
      for (int j = 0; j < 8; ++j) {
        float a = acc8[j] + lb1[j];
        a = a > 0.f ? a : 0.f;
        sv = fmaf(a, lW2[j], sv);
      }
      float pv = 1.0f / (1.0f + expf(-sv));
      p[c] = pv;
      float pm = *pmsum / (float)N;
      float y = (float)labels[c];
      float w = y * (1.f - pm) + (1.f - y) * pm;
      float pc = fminf(fmaxf(pv, 1e-7f), 1.f - 1e-7f);
      float bce = -(y * logf(pc) + (1.f - y) * logf(1.f - pc));
      contrib = w * bce / (float)N;
    }
  }
#pragma unroll
  for (int o = 32; o > 0; o >>= 1) contrib += __shfl_down(contrib, o);
  __shared__ float sh[4];
  int wv = threadIdx.x >> 6;
  if (lane == 0) sh[wv] = contrib;
  __syncthreads();
  if (threadIdx.x == 0) atomicAdd(loss, sh[0] + sh[1] + sh[2] + sh[3]);
}

// ---------------- launch ----------------

extern "C" void kernel_launch(void* const* d_in, const int* in_sizes, int n_in,
                              void* d_out, int out_size, void* d_ws, size_t ws_size,
                              hipStream_t stream) {
  const float* x      = (const float*)d_in[0];
  const int*   ei     = (const int*)d_in[1];
  const int*   labels = (const int*)d_in[2];
  const float* W1 = (const float*)d_in[3];
  const float* b1 = (const float*)d_in[4];
  const float* W2 = (const float*)d_in[5];
  const float* b2 = (const float*)d_in[6];
  const float* W3 = (const float*)d_in[7];
  const float* b3 = (const float*)d_in[8];
  const float* lW1 = (const float*)d_in[9];
  const float* lb1 = (const float*)d_in[10];
  const float* lW2 = (const float*)d_in[11];
  const float* lb2 = (const float*)d_in[12];

  int N = in_sizes[2];            // labels: [N,1]
  int E = in_sizes[1] / 2;        // edge_index: [2,E]
  const int* rows = ei;           // sources
  const int* cols = ei + E;       // targets (aggregation)

  int Npad = (N + 63) & ~63;
  int NBUCK = (N + 255) >> 8;               // 256-node buckets
  int totalH = NBUCK * NBLK;                // histogram entries
  int nb2 = (totalH + 255) / 256;

  // workspace layout: A8 buffers have one extra zero-row at index Npad (gather clamp)
  size_t a8stride = (size_t)Npad * 64 + 256;
  char* ws = (char*)d_ws;
  unsigned char*  A8a = (unsigned char*)ws;
  unsigned char*  A8b = (unsigned char*)(ws + a8stride);
  unsigned short* Wt1 = (unsigned short*)(ws + (size_t)Npad * 192); // 64*128
  unsigned short* Wt2 = Wt1 + 64 * 128;                 // 64*64
  unsigned short* Wt3 = Wt2 + 64 * 64;                  // 64*64
  float* dinv     = (float*)(Wt3 + 64 * 64);            // N
  int*   offsets  = (int*)(dinv + N);                   // N+1
  int*   histG    = offsets + N + 1;                    // NBLK*NBUCK
  int*   scanned  = histG + totalH;                     // NBLK*NBUCK
  unsigned int* packed = (unsigned int*)(scanned + totalH);  // E
  int*   sorted   = (int*)(packed + E);                 // E
  int*   partials = sorted + E;                         // nb2
  float* pmsum    = (float*)(partials + nb2);           // 1
  float* labelsum = pmsum + 1;                          // NBLK

  float* loss = (float*)d_out;
  float* p    = (float*)d_out + 1;

  int aggBlocks  = (N + 63) / 64;
  int ZR = Npad;                   // zero-row index

  // ---- atomic-free CSR build (+ Wt transpose, zero-rows & label-sum folded into hist) ----
  hist_kernel<<<NBLK, 256, 0, stream>>>(cols, histG, labels, labelsum,
                                        W1, W2, W3, Wt1, Wt2, Wt3,
                                        A8a + (size_t)Npad * 64, A8b + (size_t)Npad * 64,
                                        E, N, NBUCK);
  scan_partials_t<<<nb2, 256, 0, stream>>>(histG, partials, totalH, NBUCK);
  scan_block<<<1, 256, 0, stream>>>(partials, nb2, loss, labelsum, pmsum);
  scan_final_t<<<nb2, 256, 0, stream>>>(histG, partials, scanned, totalH, NBUCK);
  scatter_kernel<<<NBLK, 256, 0, stream>>>(rows, cols, scanned, packed, E, NBUCK);

  // ---- CSR finalize + layer-1 GEMM fused (dinv is bucket-local) ----
  csr_finalize_gemm1<<<NBUCK, 1024, 0, stream>>>(packed, scanned, sorted, offsets, dinv,
                                                 x, Wt1, A8a, N, E, NBUCK);

  // ---- fused layers: agg1+gemm2, agg2+gemm3, agg3+head ----
  agg_gemm<<<aggBlocks, 256, 0, stream>>>(A8a, offsets, sorted, dinv, b1, Wt2, A8b, N, ZR);
  agg_gemm<<<aggBlocks, 256, 0, stream>>>(A8b, offsets, sorted, dinv, b2, Wt3, A8a, N, ZR);
  agg_head<<<aggBlocks, 256, 0, stream>>>(A8a, offsets, sorted, dinv, b3,
                                          lW1, lb1, lW2, lb2, labels, pmsum, p, loss, N, ZR);
}